// Round 11
// baseline (364.053 us; speedup 1.0000x reference)
//
#include <hip/hip_runtime.h>
#include <hip/hip_bf16.h>
#include <math.h>

#define NPTS 131072

typedef short s16x8 __attribute__((ext_vector_type(8)));
typedef short s16x4 __attribute__((ext_vector_type(4)));
typedef float f32x4 __attribute__((ext_vector_type(4)));
typedef float f32x2 __attribute__((ext_vector_type(2)));
typedef int   i32x4 __attribute__((ext_vector_type(4)));

struct Planes9 { const float* p[9]; };

__device__ __forceinline__ float sp100(float h) {
    float z = 100.0f * h;
    return (fmaxf(z, 0.0f) + log1pf(__expf(-fabsf(z)))) * 0.01f;
}
// branchless softplus on z = 100*h (v_exp/v_log native)
__device__ __forceinline__ float sp100f(float z) {
    float u = __expf(-fabsf(z));
    float l = __logf(1.0f + u);
    return (fmaxf(z, 0.0f) + l) * 0.01f;
}

__device__ __forceinline__ short f2bf(float f) {
    union { float f; unsigned u; } a; a.f = f;
    unsigned u = a.u;
    return (short)((u + 0x7FFFu + ((u >> 16) & 1u)) >> 16);
}
__device__ __forceinline__ float bf2f(short h) {
    union { unsigned u; float f; } a; a.u = ((unsigned)(unsigned short)h) << 16;
    return a.f;
}
__device__ __forceinline__ short f2bf_fast(float f) {
    union { __hip_bfloat16 h; short s; } u;
    u.h = __float2bfloat16(f);
    return u.s;
}
__device__ __forceinline__ f32x2 upk2(unsigned u) {
    union { unsigned v; float f; } a, b;
    a.v = u << 16;
    b.v = u & 0xffff0000u;
    f32x2 r; r[0] = a.f; r[1] = b.f;
    return r;
}

__device__ __forceinline__ f32x4 mm(s16x8 a, s16x8 b, f32x4 c) {
    return __builtin_amdgcn_mfma_f32_16x16x32_bf16(a, b, c, 0, 0, 0);
}

// ======================= point binning: Morton 16x16x16 =======================
__device__ __forceinline__ int spread3(int v) {
    return (v & 1) | ((v & 2) << 2) | ((v & 4) << 4) | ((v & 8) << 6);
}

__global__ __launch_bounds__(256) void bin_count(
    const float* __restrict__ x, int* __restrict__ hist, int* __restrict__ binOf)
{
    int p = blockIdx.x * 256 + threadIdx.x;
    float X = x[3*p+0], Y = x[3*p+1], Z = x[3*p+2];
    int bx = min(max((int)((X + 1.0f) * 8.0f), 0), 15);
    int by = min(max((int)((Y + 1.0f) * 8.0f), 0), 15);
    int bz = min(max((int)((Z + 1.0f) * 8.0f), 0), 15);
    int bin = spread3(bx) | (spread3(by) << 1) | (spread3(bz) << 2);
    binOf[p] = bin;
    atomicAdd(&hist[bin], 1);
}

__global__ __launch_bounds__(1024) void scan_bins(
    const int* __restrict__ hist, int* __restrict__ cursor)
{
    __shared__ int a[1024];
    int t = threadIdx.x;
    int h0 = hist[4*t+0], h1 = hist[4*t+1], h2 = hist[4*t+2], h3 = hist[4*t+3];
    int s = h0 + h1 + h2 + h3;
    a[t] = s;
    __syncthreads();
    #pragma unroll
    for (int off = 1; off < 1024; off <<= 1) {
        int v = a[t];
        if (t >= off) v += a[t - off];
        __syncthreads();
        a[t] = v;
        __syncthreads();
    }
    int base = a[t] - s;
    cursor[4*t+0] = base;
    cursor[4*t+1] = base + h0;
    cursor[4*t+2] = base + h0 + h1;
    cursor[4*t+3] = base + h0 + h1 + h2;
}

__global__ __launch_bounds__(256) void scatter_pts(
    const int* __restrict__ binOf, int* __restrict__ cursor, int* __restrict__ perm)
{
    int p = blockIdx.x * 256 + threadIdx.x;
    int pos = atomicAdd(&cursor[binOf[p]], 1);
    perm[pos] = p;
}

// ---------------- planes (C,H,W) fp32 -> (H,W,C) bf16 ----------------
__global__ __launch_bounds__(256) void transpose_bf16(Planes9 pls, short* __restrict__ dst)
{
    __shared__ float tile[64 * 65];
    int b = blockIdx.x;
    int g = b / 1344, rem = b % 1344;
    int r, t2;
    if (rem < 64)       { r = 0; t2 = rem; }
    else if (rem < 320) { r = 1; t2 = rem - 64; }
    else                { r = 2; t2 = rem - 320; }
    int L = 64 << r;
    int wt = L >> 6;
    int y = t2 / wt, xt = t2 % wt;
    const float* sp = pls.p[g * 3 + r];
    short* dp = dst + (size_t)g * 5505024 + (r == 0 ? 0 : (r == 1 ? 262144 : 1310720));
    int t = threadIdx.x;
    int rowbase = y * L + xt * 64;
    {
        int xi = t & 63, cq = t >> 6;
        #pragma unroll
        for (int cc = 0; cc < 16; ++cc) {
            int c = cq * 16 + cc;
            tile[c * 65 + xi] = sp[(size_t)c * L * L + rowbase + xi];
        }
    }
    __syncthreads();
    {
        int ci = t & 63, xq = t >> 6;
        #pragma unroll
        for (int xx = 0; xx < 16; ++xx) {
            int xcol = xq * 16 + xx;
            dp[(size_t)(rowbase + xcol) * 64 + ci] = f2bf(tile[ci * 65 + xcol]);
        }
    }
}

// ===== fused kernel v7: 64 pts/block, 512 thr, pair-phase L1 + LDS geom table =====
// LDS: [0,32768) hB [64][256] bf16 (low 2x16KB doubles as feat pair-tile dbuf)
//      [32768,41984) geomW f32x4[576]; [41984,46592) geomM uint2[576]
__global__ __launch_bounds__(512, 4) void fused7(
    const float* __restrict__ x, const short* __restrict__ tpl,
    const int* __restrict__ perm,
    const short* __restrict__ W1h, const short* __restrict__ W1l,
    const short* __restrict__ W2h, const short* __restrict__ W2l,
    const short* __restrict__ Wlh, const short* __restrict__ Wll,
    const float* __restrict__ b1, const float* __restrict__ b2, const float* __restrict__ bl,
    float* __restrict__ out)
{
    __shared__ __align__(16) char smem[46592];
    __shared__ float xs[192];
    const int t = threadIdx.x, blk = blockIdx.x;
    if (t < 64) {
        int pi = perm[blk * 64 + t];
        xs[3*t+0] = x[3*pi+0];
        xs[3*t+1] = x[3*pi+1];
        xs[3*t+2] = x[3*pi+2];
    }
    const int w = t >> 6, ln = t & 63, s = ln & 15, g = ln >> 4;
    const int swz = (s & 7) << 4;
    const int pt = t & 63, kh = t >> 6;       // gather: point, 8-channel slice
    const int ptswz = (pt & 7) << 4;
    __syncthreads();   // xs visible

    // ---- geom table: one entry per (plane, point), computed ONCE ----
    #pragma unroll 1
    for (int e = t; e < 576; e += 512) {
        int pl = e >> 6, pp = e & 63;
        float xc0 = xs[pp*3+0], xc1 = xs[pp*3+1], xc2 = xs[pp*3+2];
        int grp = (pl >= 6) ? 2 : (pl >= 3 ? 1 : 0);
        int r = pl - grp * 3;
        int L = 64 << r;
        float u = (grp == 2) ? xc1 : xc0;
        float v = (grp == 0) ? xc1 : xc2;
        float ix = (u + 1.0f) * 0.5f * (float)(L - 1);
        float iy = (v + 1.0f) * 0.5f * (float)(L - 1);
        float ix0 = floorf(ix), iy0 = floorf(iy);
        float wx = ix - ix0, wy = iy - iy0;
        int x0 = (int)fminf(fmaxf(ix0, 0.f), (float)(L-1));
        int x1 = (int)fminf(fmaxf(ix0+1.f, 0.f), (float)(L-1));
        int y0 = (int)fminf(fmaxf(iy0, 0.f), (float)(L-1));
        int y1 = (int)fminf(fmaxf(iy0+1.f, 0.f), (float)(L-1));
        f32x4 wv;
        wv[0] = (1.f-wx)*(1.f-wy); wv[1] = wx*(1.f-wy);
        wv[2] = (1.f-wx)*wy;       wv[3] = wx*wy;
        unsigned grpoff = (unsigned)grp * 5505024u + (r == 0 ? 0u : (r == 1 ? 262144u : 1310720u));
        unsigned base = (grpoff + (unsigned)(y0*L + x0) * 64u) * 2u;
        unsigned dx = (unsigned)(x1 - x0) * 128u;
        unsigned dy = (unsigned)(y1 - y0) * (unsigned)L * 128u;
        *(f32x4*)(smem + 32768 + e*16) = wv;
        uint2 mm2; mm2.x = base; mm2.y = dx | (dy << 16);
        *(uint2*)(smem + 41984 + e*8) = mm2;
    }

    f32x4 acc[4][2];
    const f32x4 fz = {0.f, 0.f, 0.f, 0.f};
    #pragma unroll
    for (int mt = 0; mt < 4; ++mt)
        #pragma unroll
        for (int j = 0; j < 2; ++j) acc[mt][j] = fz;
    __syncthreads();   // geom table ready

    f32x4 wA, wB;
    i32x4 preA[4], preB[4];

#define ISSUE(SL, PL) do { \
        int e_ = (PL)*64 + pt; \
        w##SL = *(const f32x4*)(smem + 32768 + e_*16); \
        uint2 m_ = *(const uint2*)(smem + 41984 + e_*8); \
        const char* pb_ = (const char*)tpl + m_.x + kh*16; \
        unsigned dx_ = m_.y & 0xffffu, dy_ = m_.y >> 16; \
        pre##SL[0] = *(const i32x4*)pb_; \
        pre##SL[1] = *(const i32x4*)(pb_ + dx_); \
        pre##SL[2] = *(const i32x4*)(pb_ + dy_); \
        pre##SL[3] = *(const i32x4*)(pb_ + dx_ + dy_); \
    } while (0)
#define INTERP(SL, FB, IP) do { \
        s16x8 hi8_; \
        _Pragma("unroll") \
        for (int q = 0; q < 4; ++q) { \
            f32x2 v_ = upk2((unsigned)pre##SL[0][q]) * w##SL[0] \
                     + upk2((unsigned)pre##SL[1][q]) * w##SL[1] \
                     + upk2((unsigned)pre##SL[2][q]) * w##SL[2] \
                     + upk2((unsigned)pre##SL[3][q]) * w##SL[3]; \
            hi8_[q*2]   = f2bf_fast(v_[0]); \
            hi8_[q*2+1] = f2bf_fast(v_[1]); \
        } \
        *(s16x8*)((FB) + pt*256 + (IP)*128 + ((kh*16) ^ ptswz)) = hi8_; \
    } while (0)

    ISSUE(A, 0);
    ISSUE(B, 1);

    // ===== Layer 1: 4 pair-phases + 1 tail, 1 barrier/phase, 2-term (Wh+Wl)*Bh =====
    #pragma unroll 1
    for (int P = 0; P < 4; ++P) {
        char* ft = smem + ((P & 1) << 14);
        INTERP(A, ft, 0);
        ISSUE(A, 2*P + 2);                 // P=3 issues plane 8 for the tail
        INTERP(B, ft, 1);
        if (P < 3) ISSUE(B, 2*P + 3);
        __syncthreads();

        #pragma unroll
        for (int ip = 0; ip < 2; ++ip) {
            #pragma unroll
            for (int ks = 0; ks < 2; ++ks) {
                s16x8 B[4];
                #pragma unroll
                for (int mt = 0; mt < 4; ++mt)
                    B[mt] = *(s16x8*)(ft + (mt*16 + s)*256 + ip*128 + ((ks*64 + g*16) ^ swz));
                #pragma unroll
                for (int j = 0; j < 2; ++j) {
                    size_t ro = (size_t)((8*j + w)*16 + s) * 576
                              + (size_t)((2*P + ip)*64 + ks*32 + g*8);
                    s16x8 Ah = *(const s16x8*)(W1h + ro);
                    s16x8 Al = *(const s16x8*)(W1l + ro);
                    #pragma unroll
                    for (int mt = 0; mt < 4; ++mt) {
                        acc[mt][j] = mm(Ah, B[mt], acc[mt][j]);
                        acc[mt][j] = mm(Al, B[mt], acc[mt][j]);
                    }
                }
            }
        }
    }
    // tail: plane 8
    {
        char* ft = smem;                   // (P=4)&1 == 0
        INTERP(A, ft, 0);
        __syncthreads();
        #pragma unroll
        for (int ks = 0; ks < 2; ++ks) {
            s16x8 B[4];
            #pragma unroll
            for (int mt = 0; mt < 4; ++mt)
                B[mt] = *(s16x8*)(ft + (mt*16 + s)*256 + ((ks*64 + g*16) ^ swz));
            #pragma unroll
            for (int j = 0; j < 2; ++j) {
                size_t ro = (size_t)((8*j + w)*16 + s) * 576
                          + (size_t)(8*64 + ks*32 + g*8);
                s16x8 Ah = *(const s16x8*)(W1h + ro);
                s16x8 Al = *(const s16x8*)(W1l + ro);
                #pragma unroll
                for (int mt = 0; mt < 4; ++mt) {
                    acc[mt][j] = mm(Ah, B[mt], acc[mt][j]);
                    acc[mt][j] = mm(Al, B[mt], acc[mt][j]);
                }
            }
        }
    }
#undef ISSUE
#undef INTERP
    __syncthreads();   // all feat-tile reads done before hB overwrite

    // ======== bias + softplus, stage h1 (bf16) to hB [64 pt][256 k] ========
    #pragma unroll
    for (int j = 0; j < 2; ++j) {
        f32x4 bv = *(const f32x4*)(b1 + (8*j + w)*16 + g*4);
        #pragma unroll
        for (int mt = 0; mt < 4; ++mt) {
            f32x4 a = acc[mt][j];
            s16x4 hq;
            hq[0] = f2bf_fast(sp100f((a[0] + bv[0]) * 100.0f));
            hq[1] = f2bf_fast(sp100f((a[1] + bv[1]) * 100.0f));
            hq[2] = f2bf_fast(sp100f((a[2] + bv[2]) * 100.0f));
            hq[3] = f2bf_fast(sp100f((a[3] + bv[3]) * 100.0f));
            int off = (mt*16 + s)*512 + ((((8*j + w)*32) + g*8) ^ swz);
            *(s16x4*)(smem + off) = hq;
        }
    }
    #pragma unroll
    for (int mt = 0; mt < 4; ++mt)
        #pragma unroll
        for (int j = 0; j < 2; ++j) acc[mt][j] = fz;
    __syncthreads();

    // ---------------- Layer 2: K = 256, split weights (2-term) ----------------
    #pragma unroll 1
    for (int ks = 0; ks < 8; ++ks) {
        s16x8 B[4];
        #pragma unroll
        for (int mt = 0; mt < 4; ++mt) {
            int off = (mt*16 + s)*512 + ((ks*64 + g*16) ^ swz);
            B[mt] = *(s16x8*)(smem + off);
        }
        #pragma unroll
        for (int j = 0; j < 2; ++j) {
            size_t ro = (size_t)((8*j + w)*16 + s) * 256 + (size_t)(ks*32 + g*8);
            s16x8 Ah = *(const s16x8*)(W2h + ro);
            s16x8 Al = *(const s16x8*)(W2l + ro);
            #pragma unroll
            for (int mt = 0; mt < 4; ++mt) {
                acc[mt][j] = mm(Ah, B[mt], acc[mt][j]);
                acc[mt][j] = mm(Al, B[mt], acc[mt][j]);
            }
        }
    }
    __syncthreads();   // all hB reads done before overwrite with h2

    // ======== bias + softplus, stage h2 ========
    #pragma unroll
    for (int j = 0; j < 2; ++j) {
        f32x4 bv = *(const f32x4*)(b2 + (8*j + w)*16 + g*4);
        #pragma unroll
        for (int mt = 0; mt < 4; ++mt) {
            f32x4 a = acc[mt][j];
            s16x4 hq;
            hq[0] = f2bf_fast(sp100f((a[0] + bv[0]) * 100.0f));
            hq[1] = f2bf_fast(sp100f((a[1] + bv[1]) * 100.0f));
            hq[2] = f2bf_fast(sp100f((a[2] + bv[2]) * 100.0f));
            hq[3] = f2bf_fast(sp100f((a[3] + bv[3]) * 100.0f));
            int off = (mt*16 + s)*512 + ((((8*j + w)*32) + g*8) ^ swz);
            *(s16x4*)(smem + off) = hq;
        }
    }
    __syncthreads();

    // ------- Layer 3: Wl padded to 128 rows (8 tiles); wave w owns tile w -------
    f32x4 acc3[4];
    #pragma unroll
    for (int mt = 0; mt < 4; ++mt) acc3[mt] = fz;
    #pragma unroll 1
    for (int ks = 0; ks < 8; ++ks) {
        s16x8 B[4];
        #pragma unroll
        for (int mt = 0; mt < 4; ++mt) {
            int off = (mt*16 + s)*512 + ((ks*64 + g*16) ^ swz);
            B[mt] = *(s16x8*)(smem + off);
        }
        size_t ro = (size_t)(w*16 + s) * 256 + (size_t)(ks*32 + g*8);
        s16x8 Ah = *(const s16x8*)(Wlh + ro);
        s16x8 Al = *(const s16x8*)(Wll + ro);
        #pragma unroll
        for (int mt = 0; mt < 4; ++mt) {
            acc3[mt] = mm(Ah, B[mt], acc3[mt]);
            acc3[mt] = mm(Al, B[mt], acc3[mt]);
        }
    }

    // ---------------- output: feat (P,64) + dsdf (P,1), perm-scattered ----------------
    if (w < 4) {
        f32x4 bv = *(const f32x4*)(bl + w*16 + g*4);
        #pragma unroll
        for (int mt = 0; mt < 4; ++mt) {
            int pl_ = blk*64 + mt*16 + s;
            size_t p = (size_t)perm[pl_];
            f32x4 o = acc3[mt];
            o[0] += bv[0]; o[1] += bv[1]; o[2] += bv[2]; o[3] += bv[3];
            *(f32x4*)(out + p*64 + (size_t)(w*16 + g*4)) = o;
        }
    } else if (w == 4 && g == 0) {
        float bld = bl[64];
        #pragma unroll
        for (int mt = 0; mt < 4; ++mt) {
            int pl_ = blk*64 + mt*16 + s;
            size_t p = (size_t)perm[pl_];
            out[(size_t)NPTS*64 + p] = acc3[mt][0] + bld;
        }
    }
}

// ================= fallback (R6-validated, fp32 planes, identity order) ==============
__global__ __launch_bounds__(256, 4) void fused3f(
    const float* __restrict__ x, Planes9 pls,
    const short* __restrict__ W1h, const short* __restrict__ W1l,
    const short* __restrict__ W2h, const short* __restrict__ W2l,
    const short* __restrict__ Wlh, const short* __restrict__ Wll,
    const float* __restrict__ b1, const float* __restrict__ b2, const float* __restrict__ bl,
    float* __restrict__ out)
{
    __shared__ __align__(16) char smem[32768];
    __shared__ float xs[192];
    const int t = threadIdx.x, blk = blockIdx.x;
    if (t < 64) {
        int pi = blk * 64 + t;
        xs[3*t+0] = x[3*pi+0];
        xs[3*t+1] = x[3*pi+1];
        xs[3*t+2] = x[3*pi+2];
    }
    const int w = t >> 6, ln = t & 63, s = ln & 15, g = ln >> 4;
    const int swz = (s & 7) << 4;
    const int pt = t & 63, kh = t >> 6;
    const int ptswz = (pt & 7) << 4;

    f32x4 acc[4][4];
    const f32x4 fz = {0.f, 0.f, 0.f, 0.f};
    #pragma unroll
    for (int mt = 0; mt < 4; ++mt)
        #pragma unroll
        for (int j = 0; j < 4; ++j) acc[mt][j] = fz;
    __syncthreads();

    #pragma unroll 1
    for (int pl = 0; pl < 9; ++pl) {
        const int grp = (pl >= 6) ? 2 : (pl >= 3 ? 1 : 0);
        const int r = pl - grp * 3;
        const int L = 64 << r;
        float u, v;
        { float a0 = xs[pt*3+0], a1 = xs[pt*3+1], a2 = xs[pt*3+2];
          u = (grp == 2) ? a1 : a0;
          v = (grp == 0) ? a1 : a2; }
        float ix = (u + 1.0f) * 0.5f * (float)(L - 1);
        float iy = (v + 1.0f) * 0.5f * (float)(L - 1);
        float ix0 = floorf(ix), iy0 = floorf(iy);
        float wx = ix - ix0, wy = iy - iy0;
        int x0 = (int)fminf(fmaxf(ix0, 0.f), (float)(L-1));
        int x1 = (int)fminf(fmaxf(ix0+1.f, 0.f), (float)(L-1));
        int y0 = (int)fminf(fmaxf(iy0, 0.f), (float)(L-1));
        int y1 = (int)fminf(fmaxf(iy0+1.f, 0.f), (float)(L-1));
        float wnw = (1.f-wx)*(1.f-wy), wne = wx*(1.f-wy), wsw = (1.f-wx)*wy, wse = wx*wy;

        const float* P = pls.p[pl];
        const int i00 = y0*L+x0, i01 = y0*L+x1, i10 = y1*L+x0, i11 = y1*L+x1;
        float f[16];
        #pragma unroll 8
        for (int c = 0; c < 16; ++c) {
            const float* pc = P + (size_t)(kh*16 + c) * L * L;
            f[c] = wnw*pc[i00] + wne*pc[i01] + wsw*pc[i10] + wse*pc[i11];
        }
        #pragma unroll
        for (int q = 0; q < 2; ++q) {
            s16x8 hi8;
            #pragma unroll
            for (int e = 0; e < 8; ++e) hi8[e] = f2bf_fast(f[q*8+e]);
            int off = pt*128 + ((kh*32 + q*16) ^ ptswz);
            *(s16x8*)(smem + off) = hi8;
        }
        __syncthreads();

        #pragma unroll
        for (int ks = 0; ks < 2; ++ks) {
            s16x8 B[4];
            #pragma unroll
            for (int mt = 0; mt < 4; ++mt)
                B[mt] = *(s16x8*)(smem + (mt*16 + s)*128 + ((ks*64 + g*16) ^ swz));
            #pragma unroll
            for (int j = 0; j < 4; ++j) {
                size_t ro = (size_t)((4*j + w)*16 + s) * 576 + (size_t)(pl*64 + ks*32 + g*8);
                s16x8 Ah = *(const s16x8*)(W1h + ro);
                s16x8 Al = *(const s16x8*)(W1l + ro);
                #pragma unroll
                for (int mt = 0; mt < 4; ++mt) {
                    acc[mt][j] = mm(Ah, B[mt], acc[mt][j]);
                    acc[mt][j] = mm(Al, B[mt], acc[mt][j]);
                }
            }
        }
        __syncthreads();
    }

    #pragma unroll
    for (int j = 0; j < 4; ++j) {
        f32x4 bv = *(const f32x4*)(b1 + (4*j + w)*16 + g*4);
        #pragma unroll
        for (int mt = 0; mt < 4; ++mt) {
            f32x4 a = acc[mt][j];
            s16x4 hq;
            hq[0] = f2bf_fast(sp100(a[0] + bv[0]));
            hq[1] = f2bf_fast(sp100(a[1] + bv[1]));
            hq[2] = f2bf_fast(sp100(a[2] + bv[2]));
            hq[3] = f2bf_fast(sp100(a[3] + bv[3]));
            int off = (mt*16 + s)*512 + ((((4*j + w)*32) + g*8) ^ swz);
            *(s16x4*)(smem + off) = hq;
        }
    }
    #pragma unroll
    for (int mt = 0; mt < 4; ++mt)
        #pragma unroll
        for (int j = 0; j < 4; ++j) acc[mt][j] = fz;
    __syncthreads();

    #pragma unroll 1
    for (int ks = 0; ks < 8; ++ks) {
        s16x8 B[4];
        #pragma unroll
        for (int mt = 0; mt < 4; ++mt)
            B[mt] = *(s16x8*)(smem + (mt*16 + s)*512 + ((ks*64 + g*16) ^ swz));
        #pragma unroll
        for (int j = 0; j < 4; ++j) {
            size_t ro = (size_t)((4*j + w)*16 + s) * 256 + (size_t)(ks*32 + g*8);
            s16x8 Ah = *(const s16x8*)(W2h + ro);
            s16x8 Al = *(const s16x8*)(W2l + ro);
            #pragma unroll
            for (int mt = 0; mt < 4; ++mt) {
                acc[mt][j] = mm(Ah, B[mt], acc[mt][j]);
                acc[mt][j] = mm(Al, B[mt], acc[mt][j]);
            }
        }
    }
    __syncthreads();

    #pragma unroll
    for (int j = 0; j < 4; ++j) {
        f32x4 bv = *(const f32x4*)(b2 + (4*j + w)*16 + g*4);
        #pragma unroll
        for (int mt = 0; mt < 4; ++mt) {
            f32x4 a = acc[mt][j];
            s16x4 hq;
            hq[0] = f2bf_fast(sp100(a[0] + bv[0]));
            hq[1] = f2bf_fast(sp100(a[1] + bv[1]));
            hq[2] = f2bf_fast(sp100(a[2] + bv[2]));
            hq[3] = f2bf_fast(sp100(a[3] + bv[3]));
            int off = (mt*16 + s)*512 + ((((4*j + w)*32) + g*8) ^ swz);
            *(s16x4*)(smem + off) = hq;
        }
    }
    __syncthreads();

    f32x4 acc3[4][2];
    #pragma unroll
    for (int mt = 0; mt < 4; ++mt) { acc3[mt][0] = fz; acc3[mt][1] = fz; }
    #pragma unroll 1
    for (int ks = 0; ks < 8; ++ks) {
        s16x8 B[4];
        #pragma unroll
        for (int mt = 0; mt < 4; ++mt)
            B[mt] = *(s16x8*)(smem + (mt*16 + s)*512 + ((ks*64 + g*16) ^ swz));
        #pragma unroll
        for (int j = 0; j < 2; ++j) {
            size_t ro = (size_t)((4*j + w)*16 + s) * 256 + (size_t)(ks*32 + g*8);
            s16x8 Ah = *(const s16x8*)(Wlh + ro);
            s16x8 Al = *(const s16x8*)(Wll + ro);
            #pragma unroll
            for (int mt = 0; mt < 4; ++mt) {
                acc3[mt][j] = mm(Ah, B[mt], acc3[mt][j]);
                acc3[mt][j] = mm(Al, B[mt], acc3[mt][j]);
            }
        }
    }

    {
        f32x4 bv = *(const f32x4*)(bl + w*16 + g*4);
        #pragma unroll
        for (int mt = 0; mt < 4; ++mt) {
            size_t p = (size_t)(blk*64 + mt*16 + s);
            f32x4 o = acc3[mt][0];
            o[0] += bv[0]; o[1] += bv[1]; o[2] += bv[2]; o[3] += bv[3];
            *(f32x4*)(out + p*64 + (size_t)(w*16 + g*4)) = o;
            if (w == 0 && g == 0)
                out[(size_t)NPTS*64 + p] = acc3[mt][1][0] + bl[64];
        }
    }
}

// ---------------- weight-norm + bf16 hi/lo split (row-major n x k) -------
__global__ __launch_bounds__(64) void prep_weights(
    const float* __restrict__ v1, const float* __restrict__ g1,
    const float* __restrict__ v2, const float* __restrict__ g2,
    const float* __restrict__ vl, const float* __restrict__ gl,
    short* __restrict__ W1h, short* __restrict__ W1l,
    short* __restrict__ W2h, short* __restrict__ W2l,
    short* __restrict__ Wlh, short* __restrict__ Wll)
{
    int i = blockIdx.x, t = threadIdx.x;
    const float* src; float gv; int K; short *dh, *dl; size_t ro;
    if (i < 256)      { src = v1 + (size_t)i*576; gv = g1[i]; K = 576; dh = W1h; dl = W1l; ro = (size_t)i*576; }
    else if (i < 512) { int rr = i-256; src = v2 + (size_t)rr*256; gv = g2[rr]; K = 256; dh = W2h; dl = W2l; ro = (size_t)rr*256; }
    else {
        int rr = i-512;
        K = 256; dh = Wlh; dl = Wll; ro = (size_t)rr*256;
        if (rr >= 65) {
            for (int k = t; k < 256; k += 64) { dh[ro+k] = 0; dl[ro+k] = 0; }
            return;
        }
        src = vl + (size_t)rr*256; gv = gl[rr];
    }
    float ssum = 0.f;
    for (int k = t; k < K; k += 64) { float wv = src[k]; ssum += wv*wv; }
    #pragma unroll
    for (int off = 32; off > 0; off >>= 1) ssum += __shfl_xor(ssum, off, 64);
    float sc = gv / sqrtf(ssum);
    for (int k = t; k < K; k += 64) {
        float wv = src[k] * sc;
        short hb = f2bf(wv);
        dh[ro + k] = hb;
        dl[ro + k] = f2bf(wv - bf2f(hb));
    }
}

extern "C" void kernel_launch(void* const* d_in, const int* in_sizes, int n_in,
                              void* d_out, int out_size, void* d_ws, size_t ws_size,
                              hipStream_t stream)
{
    const float* x = (const float*)d_in[0];
    Planes9 pls;
    for (int i = 0; i < 9; ++i) pls.p[i] = (const float*)d_in[1 + i];
    const float* v1 = (const float*)d_in[10];
    const float* g1 = (const float*)d_in[11];
    const float* b1 = (const float*)d_in[12];
    const float* v2 = (const float*)d_in[13];
    const float* g2 = (const float*)d_in[14];
    const float* b2 = (const float*)d_in[15];
    const float* vl = (const float*)d_in[16];
    const float* gl = (const float*)d_in[17];
    const float* bl = (const float*)d_in[18];

    short* ws16 = (short*)d_ws;
    short* W1h = ws16;                    // 256*576
    short* W1l = ws16 + 147456;
    short* W2h = ws16 + 294912;           // 256*256
    short* W2l = ws16 + 360448;
    short* Wlh = ws16 + 425984;           // 128*256 (padded)
    short* Wll = ws16 + 458752;
    short* tpl = ws16 + 491520;           // bf16 transposed planes: 16515072 shorts
    const size_t w_bytes   = (size_t)491520 * 2;
    const size_t tpl_bytes = (size_t)16515072 * 2;
    int* hist   = (int*)((char*)d_ws + w_bytes + tpl_bytes);
    int* cursor = hist + 4096;
    int* binOf  = cursor + 4096;
    int* perm   = binOf + 131072;
    const size_t need = w_bytes + tpl_bytes + (4096*2 + 131072*2) * sizeof(int);

    prep_weights<<<640, 64, 0, stream>>>(v1, g1, v2, g2, vl, gl,
                                         W1h, W1l, W2h, W2l, Wlh, Wll);

    if (ws_size >= need) {
        transpose_bf16<<<4032, 256, 0, stream>>>(pls, tpl);
        hipError_t e = hipMemsetAsync(hist, 0, 4096 * sizeof(int), stream); (void)e;
        bin_count<<<NPTS / 256, 256, 0, stream>>>(x, hist, binOf);
        scan_bins<<<1, 1024, 0, stream>>>(hist, cursor);
        scatter_pts<<<NPTS / 256, 256, 0, stream>>>(binOf, cursor, perm);
        fused7<<<NPTS / 64, 512, 0, stream>>>(x, tpl, perm,
                                              W1h, W1l, W2h, W2l, Wlh, Wll,
                                              b1, b2, bl, (float*)d_out);
    } else {
        fused3f<<<NPTS / 64, 256, 0, stream>>>(x, pls,
                                               W1h, W1l, W2h, W2l, Wlh, Wll,
                                               b1, b2, bl, (float*)d_out);
    }
}

// Round 12
// 263.681 us; speedup vs baseline: 1.3807x; 1.3807x over previous
//
#include <hip/hip_runtime.h>
#include <hip/hip_bf16.h>
#include <math.h>

#define NPTS 131072

typedef short s16x8 __attribute__((ext_vector_type(8)));
typedef short s16x4 __attribute__((ext_vector_type(4)));
typedef float f32x4 __attribute__((ext_vector_type(4)));
typedef float f32x2 __attribute__((ext_vector_type(2)));
typedef int   i32x4 __attribute__((ext_vector_type(4)));

struct Planes9 { const float* p[9]; };

__device__ __forceinline__ float sp100(float h) {
    float z = 100.0f * h;
    return (fmaxf(z, 0.0f) + log1pf(__expf(-fabsf(z)))) * 0.01f;
}
// branchless softplus on z = 100*h (v_exp/v_log native)
__device__ __forceinline__ float sp100f(float z) {
    float u = __expf(-fabsf(z));
    float l = __logf(1.0f + u);
    return (fmaxf(z, 0.0f) + l) * 0.01f;
}

__device__ __forceinline__ short f2bf(float f) {
    union { float f; unsigned u; } a; a.f = f;
    unsigned u = a.u;
    return (short)((u + 0x7FFFu + ((u >> 16) & 1u)) >> 16);
}
__device__ __forceinline__ float bf2f(short h) {
    union { unsigned u; float f; } a; a.u = ((unsigned)(unsigned short)h) << 16;
    return a.f;
}
__device__ __forceinline__ short f2bf_fast(float f) {
    union { __hip_bfloat16 h; short s; } u;
    u.h = __float2bfloat16(f);
    return u.s;
}
__device__ __forceinline__ f32x2 upk2(unsigned u) {
    union { unsigned v; float f; } a, b;
    a.v = u << 16;
    b.v = u & 0xffff0000u;
    f32x2 r; r[0] = a.f; r[1] = b.f;
    return r;
}

__device__ __forceinline__ f32x4 mm(s16x8 a, s16x8 b, f32x4 c) {
    return __builtin_amdgcn_mfma_f32_16x16x32_bf16(a, b, c, 0, 0, 0);
}

// ======================= point binning: Morton 16x16x16 =======================
__device__ __forceinline__ int spread3(int v) {
    return (v & 1) | ((v & 2) << 2) | ((v & 4) << 4) | ((v & 8) << 6);
}

__global__ __launch_bounds__(256) void bin_count(
    const float* __restrict__ x, int* __restrict__ hist, int* __restrict__ binOf)
{
    int p = blockIdx.x * 256 + threadIdx.x;
    float X = x[3*p+0], Y = x[3*p+1], Z = x[3*p+2];
    int bx = min(max((int)((X + 1.0f) * 8.0f), 0), 15);
    int by = min(max((int)((Y + 1.0f) * 8.0f), 0), 15);
    int bz = min(max((int)((Z + 1.0f) * 8.0f), 0), 15);
    int bin = spread3(bx) | (spread3(by) << 1) | (spread3(bz) << 2);
    binOf[p] = bin;
    atomicAdd(&hist[bin], 1);
}

__global__ __launch_bounds__(1024) void scan_bins(
    const int* __restrict__ hist, int* __restrict__ cursor)
{
    __shared__ int a[1024];
    int t = threadIdx.x;
    int h0 = hist[4*t+0], h1 = hist[4*t+1], h2 = hist[4*t+2], h3 = hist[4*t+3];
    int s = h0 + h1 + h2 + h3;
    a[t] = s;
    __syncthreads();
    #pragma unroll
    for (int off = 1; off < 1024; off <<= 1) {
        int v = a[t];
        if (t >= off) v += a[t - off];
        __syncthreads();
        a[t] = v;
        __syncthreads();
    }
    int base = a[t] - s;
    cursor[4*t+0] = base;
    cursor[4*t+1] = base + h0;
    cursor[4*t+2] = base + h0 + h1;
    cursor[4*t+3] = base + h0 + h1 + h2;
}

__global__ __launch_bounds__(256) void scatter_pts(
    const int* __restrict__ binOf, int* __restrict__ cursor, int* __restrict__ perm)
{
    int p = blockIdx.x * 256 + threadIdx.x;
    int pos = atomicAdd(&cursor[binOf[p]], 1);
    perm[pos] = p;
}

// ---------------- planes (C,H,W) fp32 -> (H,W,C) bf16 ----------------
__global__ __launch_bounds__(256) void transpose_bf16(Planes9 pls, short* __restrict__ dst)
{
    __shared__ float tile[64 * 65];
    int b = blockIdx.x;
    int g = b / 1344, rem = b % 1344;
    int r, t2;
    if (rem < 64)       { r = 0; t2 = rem; }
    else if (rem < 320) { r = 1; t2 = rem - 64; }
    else                { r = 2; t2 = rem - 320; }
    int L = 64 << r;
    int wt = L >> 6;
    int y = t2 / wt, xt = t2 % wt;
    const float* sp = pls.p[g * 3 + r];
    short* dp = dst + (size_t)g * 5505024 + (r == 0 ? 0 : (r == 1 ? 262144 : 1310720));
    int t = threadIdx.x;
    int rowbase = y * L + xt * 64;
    {
        int xi = t & 63, cq = t >> 6;
        #pragma unroll
        for (int cc = 0; cc < 16; ++cc) {
            int c = cq * 16 + cc;
            tile[c * 65 + xi] = sp[(size_t)c * L * L + rowbase + xi];
        }
    }
    __syncthreads();
    {
        int ci = t & 63, xq = t >> 6;
        #pragma unroll
        for (int xx = 0; xx < 16; ++xx) {
            int xcol = xq * 16 + xx;
            dp[(size_t)(rowbase + xcol) * 64 + ci] = f2bf(tile[ci * 65 + xcol]);
        }
    }
}

// per-plane bilerp geometry (bf16 transposed planes); kh in 0..7 -> 8-ch slice
__device__ __forceinline__ void plane_geom(
    int pl, float xc0, float xc1, float xc2, const short* __restrict__ tpl, int kh,
    float& wnw, float& wne, float& wsw, float& wse,
    const short*& pNW, const short*& pNE, const short*& pSW, const short*& pSE)
{
    const int grp = (pl >= 6) ? 2 : (pl >= 3 ? 1 : 0);
    const int r = pl - grp * 3;
    const int L = 64 << r;
    const float u = (grp == 2) ? xc1 : xc0;
    const float v = (grp == 0) ? xc1 : xc2;
    float ix = (u + 1.0f) * 0.5f * (float)(L - 1);
    float iy = (v + 1.0f) * 0.5f * (float)(L - 1);
    float ix0 = floorf(ix), iy0 = floorf(iy);
    float wx = ix - ix0, wy = iy - iy0;
    int x0 = (int)fminf(fmaxf(ix0, 0.f), (float)(L-1));
    int x1 = (int)fminf(fmaxf(ix0+1.f, 0.f), (float)(L-1));
    int y0 = (int)fminf(fmaxf(iy0, 0.f), (float)(L-1));
    int y1 = (int)fminf(fmaxf(iy0+1.f, 0.f), (float)(L-1));
    wnw = (1.f-wx)*(1.f-wy); wne = wx*(1.f-wy); wsw = (1.f-wx)*wy; wse = wx*wy;
    const short* TP = tpl + (size_t)grp * 5505024
                    + (r == 0 ? 0u : (r == 1 ? 262144u : 1310720u));
    pNW = TP + ((size_t)(y0*L + x0) * 64 + kh*8);
    pNE = TP + ((size_t)(y0*L + x1) * 64 + kh*8);
    pSW = TP + ((size_t)(y1*L + x0) * 64 + kh*8);
    pSE = TP + ((size_t)(y1*L + x1) * 64 + kh*8);
}

// ===== fused kernel v8: fused6 structure + W-hi-only MFMA (240 MFMA/wave) =====
__global__ __launch_bounds__(512, 4) void fused8(
    const float* __restrict__ x, const short* __restrict__ tpl,
    const int* __restrict__ perm,
    const short* __restrict__ W1h,
    const short* __restrict__ W2h,
    const short* __restrict__ Wlh,
    const float* __restrict__ b1, const float* __restrict__ b2, const float* __restrict__ bl,
    float* __restrict__ out)
{
    // hB [64 pt][256 k] bf16 (32 KB); L1 feat dbuf 2 x 8 KB aliases its low half
    __shared__ __align__(16) char smem[32768];
    __shared__ float xs[192];
    const int t = threadIdx.x, blk = blockIdx.x;
    if (t < 64) {
        int pi = perm[blk * 64 + t];
        xs[3*t+0] = x[3*pi+0];
        xs[3*t+1] = x[3*pi+1];
        xs[3*t+2] = x[3*pi+2];
    }
    const int w = t >> 6, ln = t & 63, s = ln & 15, g = ln >> 4;
    const int swz = (s & 7) << 4;
    const int pt = t & 63, kh = t >> 6;       // gather: point, 8-channel slice
    const int ptswz = (pt & 7) << 4;

    f32x4 acc[4][2];
    const f32x4 fz = {0.f, 0.f, 0.f, 0.f};
    #pragma unroll
    for (int mt = 0; mt < 4; ++mt)
        #pragma unroll
        for (int j = 0; j < 2; ++j) acc[mt][j] = fz;

    __syncthreads();   // xs visible

    const float xc0 = xs[pt*3+0], xc1 = xs[pt*3+1], xc2 = xs[pt*3+2];

    // two named prefetch slots (depth-2 pipeline), static indexing only
    float wA0, wA1, wA2, wA3, wB0, wB1, wB2, wB3;
    i32x4 preA[4], preB[4];
    const short *pNW, *pNE, *pSW, *pSE;

#define ISSUE_A(PL) do { \
        plane_geom(PL, xc0, xc1, xc2, tpl, kh, wA0, wA1, wA2, wA3, pNW, pNE, pSW, pSE); \
        preA[0] = *(const i32x4*)pNW; preA[1] = *(const i32x4*)pNE; \
        preA[2] = *(const i32x4*)pSW; preA[3] = *(const i32x4*)pSE; \
    } while (0)
#define ISSUE_B(PL) do { \
        plane_geom(PL, xc0, xc1, xc2, tpl, kh, wB0, wB1, wB2, wB3, pNW, pNE, pSW, pSE); \
        preB[0] = *(const i32x4*)pNW; preB[1] = *(const i32x4*)pNE; \
        preB[2] = *(const i32x4*)pSW; preB[3] = *(const i32x4*)pSE; \
    } while (0)
#define INTERP(PRE, W0, W1, W2, W3, FB) do { \
        s16x8 hi8; \
        _Pragma("unroll") \
        for (int q = 0; q < 4; ++q) { \
            f32x2 v = upk2((unsigned)PRE[0][q]) * W0 \
                    + upk2((unsigned)PRE[1][q]) * W1 \
                    + upk2((unsigned)PRE[2][q]) * W2 \
                    + upk2((unsigned)PRE[3][q]) * W3; \
            hi8[q*2]   = f2bf_fast(v[0]); \
            hi8[q*2+1] = f2bf_fast(v[1]); \
        } \
        *(s16x8*)((FB) + pt*128 + ((kh*16) ^ ptswz)) = hi8; \
    } while (0)

    ISSUE_A(0);
    ISSUE_B(1);

    // ===== Layer 1: 9 planes, dbuf feat tile, depth-2 prefetch, 1 barrier/plane =====
    #pragma unroll 1
    for (int pl = 0; pl < 9; ++pl) {
        char* fb = smem + ((pl & 1) << 13);
        if (pl & 1) {
            INTERP(preB, wB0, wB1, wB2, wB3, fb);
            if (pl < 7) ISSUE_B(pl + 2);   // 2 MFMA phases + interp to land
        } else {
            INTERP(preA, wA0, wA1, wA2, wA3, fb);
            if (pl < 7) ISSUE_A(pl + 2);
        }
        __syncthreads();

        #pragma unroll
        for (int ks = 0; ks < 2; ++ks) {
            s16x8 B[4];
            #pragma unroll
            for (int mt = 0; mt < 4; ++mt)
                B[mt] = *(s16x8*)(fb + (mt*16 + s)*128 + ((ks*64 + g*16) ^ swz));
            #pragma unroll
            for (int j = 0; j < 2; ++j) {
                size_t ro = (size_t)((8*j + w)*16 + s) * 576 + (size_t)(pl*64 + ks*32 + g*8);
                s16x8 Ah = *(const s16x8*)(W1h + ro);
                #pragma unroll
                for (int mt = 0; mt < 4; ++mt)
                    acc[mt][j] = mm(Ah, B[mt], acc[mt][j]);
            }
        }
    }
#undef ISSUE_A
#undef ISSUE_B
#undef INTERP
    __syncthreads();   // all MFMA reads of feat bufs done before hB overwrite

    // ======== bias + softplus, stage h1 (bf16) to hB [64 pt][256 k] ========
    #pragma unroll
    for (int j = 0; j < 2; ++j) {
        f32x4 bv = *(const f32x4*)(b1 + (8*j + w)*16 + g*4);
        #pragma unroll
        for (int mt = 0; mt < 4; ++mt) {
            f32x4 a = acc[mt][j];
            s16x4 hq;
            hq[0] = f2bf_fast(sp100f((a[0] + bv[0]) * 100.0f));
            hq[1] = f2bf_fast(sp100f((a[1] + bv[1]) * 100.0f));
            hq[2] = f2bf_fast(sp100f((a[2] + bv[2]) * 100.0f));
            hq[3] = f2bf_fast(sp100f((a[3] + bv[3]) * 100.0f));
            int off = (mt*16 + s)*512 + ((((8*j + w)*32) + g*8) ^ swz);
            *(s16x4*)(smem + off) = hq;
        }
    }
    #pragma unroll
    for (int mt = 0; mt < 4; ++mt)
        #pragma unroll
        for (int j = 0; j < 2; ++j) acc[mt][j] = fz;
    __syncthreads();

    // ---------------- Layer 2: K = 256, W-hi only ----------------
    #pragma unroll 1
    for (int ks = 0; ks < 8; ++ks) {
        s16x8 B[4];
        #pragma unroll
        for (int mt = 0; mt < 4; ++mt) {
            int off = (mt*16 + s)*512 + ((ks*64 + g*16) ^ swz);
            B[mt] = *(s16x8*)(smem + off);
        }
        #pragma unroll
        for (int j = 0; j < 2; ++j) {
            size_t ro = (size_t)((8*j + w)*16 + s) * 256 + (size_t)(ks*32 + g*8);
            s16x8 Ah = *(const s16x8*)(W2h + ro);
            #pragma unroll
            for (int mt = 0; mt < 4; ++mt)
                acc[mt][j] = mm(Ah, B[mt], acc[mt][j]);
        }
    }
    __syncthreads();   // all hB reads done before overwrite with h2

    // ======== bias + softplus, stage h2 ========
    #pragma unroll
    for (int j = 0; j < 2; ++j) {
        f32x4 bv = *(const f32x4*)(b2 + (8*j + w)*16 + g*4);
        #pragma unroll
        for (int mt = 0; mt < 4; ++mt) {
            f32x4 a = acc[mt][j];
            s16x4 hq;
            hq[0] = f2bf_fast(sp100f((a[0] + bv[0]) * 100.0f));
            hq[1] = f2bf_fast(sp100f((a[1] + bv[1]) * 100.0f));
            hq[2] = f2bf_fast(sp100f((a[2] + bv[2]) * 100.0f));
            hq[3] = f2bf_fast(sp100f((a[3] + bv[3]) * 100.0f));
            int off = (mt*16 + s)*512 + ((((8*j + w)*32) + g*8) ^ swz);
            *(s16x4*)(smem + off) = hq;
        }
    }
    __syncthreads();

    // ------- Layer 3: Wl padded to 128 rows (8 tiles); wave w owns tile w -------
    f32x4 acc3[4];
    #pragma unroll
    for (int mt = 0; mt < 4; ++mt) acc3[mt] = fz;
    #pragma unroll 1
    for (int ks = 0; ks < 8; ++ks) {
        s16x8 B[4];
        #pragma unroll
        for (int mt = 0; mt < 4; ++mt) {
            int off = (mt*16 + s)*512 + ((ks*64 + g*16) ^ swz);
            B[mt] = *(s16x8*)(smem + off);
        }
        size_t ro = (size_t)(w*16 + s) * 256 + (size_t)(ks*32 + g*8);
        s16x8 Ah = *(const s16x8*)(Wlh + ro);
        #pragma unroll
        for (int mt = 0; mt < 4; ++mt)
            acc3[mt] = mm(Ah, B[mt], acc3[mt]);
    }

    // ---------------- output: feat (P,64) + dsdf (P,1), perm-scattered ----------------
    if (w < 4) {
        f32x4 bv = *(const f32x4*)(bl + w*16 + g*4);
        #pragma unroll
        for (int mt = 0; mt < 4; ++mt) {
            int pl_ = blk*64 + mt*16 + s;
            size_t p = (size_t)perm[pl_];
            f32x4 o = acc3[mt];
            o[0] += bv[0]; o[1] += bv[1]; o[2] += bv[2]; o[3] += bv[3];
            *(f32x4*)(out + p*64 + (size_t)(w*16 + g*4)) = o;
        }
    } else if (w == 4 && g == 0) {
        float bld = bl[64];
        #pragma unroll
        for (int mt = 0; mt < 4; ++mt) {
            int pl_ = blk*64 + mt*16 + s;
            size_t p = (size_t)perm[pl_];
            out[(size_t)NPTS*64 + p] = acc3[mt][0] + bld;
        }
    }
}

// ================= fallback (R6-validated, fp32 planes, identity order, split W) =====
__global__ __launch_bounds__(256, 4) void fused3f(
    const float* __restrict__ x, Planes9 pls,
    const short* __restrict__ W1h, const short* __restrict__ W1l,
    const short* __restrict__ W2h, const short* __restrict__ W2l,
    const short* __restrict__ Wlh, const short* __restrict__ Wll,
    const float* __restrict__ b1, const float* __restrict__ b2, const float* __restrict__ bl,
    float* __restrict__ out)
{
    __shared__ __align__(16) char smem[32768];
    __shared__ float xs[192];
    const int t = threadIdx.x, blk = blockIdx.x;
    if (t < 64) {
        int pi = blk * 64 + t;
        xs[3*t+0] = x[3*pi+0];
        xs[3*t+1] = x[3*pi+1];
        xs[3*t+2] = x[3*pi+2];
    }
    const int w = t >> 6, ln = t & 63, s = ln & 15, g = ln >> 4;
    const int swz = (s & 7) << 4;
    const int pt = t & 63, kh = t >> 6;
    const int ptswz = (pt & 7) << 4;

    f32x4 acc[4][4];
    const f32x4 fz = {0.f, 0.f, 0.f, 0.f};
    #pragma unroll
    for (int mt = 0; mt < 4; ++mt)
        #pragma unroll
        for (int j = 0; j < 4; ++j) acc[mt][j] = fz;
    __syncthreads();

    #pragma unroll 1
    for (int pl = 0; pl < 9; ++pl) {
        const int grp = (pl >= 6) ? 2 : (pl >= 3 ? 1 : 0);
        const int r = pl - grp * 3;
        const int L = 64 << r;
        float u, v;
        { float a0 = xs[pt*3+0], a1 = xs[pt*3+1], a2 = xs[pt*3+2];
          u = (grp == 2) ? a1 : a0;
          v = (grp == 0) ? a1 : a2; }
        float ix = (u + 1.0f) * 0.5f * (float)(L - 1);
        float iy = (v + 1.0f) * 0.5f * (float)(L - 1);
        float ix0 = floorf(ix), iy0 = floorf(iy);
        float wx = ix - ix0, wy = iy - iy0;
        int x0 = (int)fminf(fmaxf(ix0, 0.f), (float)(L-1));
        int x1 = (int)fminf(fmaxf(ix0+1.f, 0.f), (float)(L-1));
        int y0 = (int)fminf(fmaxf(iy0, 0.f), (float)(L-1));
        int y1 = (int)fminf(fmaxf(iy0+1.f, 0.f), (float)(L-1));
        float wnw = (1.f-wx)*(1.f-wy), wne = wx*(1.f-wy), wsw = (1.f-wx)*wy, wse = wx*wy;

        const float* P = pls.p[pl];
        const int i00 = y0*L+x0, i01 = y0*L+x1, i10 = y1*L+x0, i11 = y1*L+x1;
        float f[16];
        #pragma unroll 8
        for (int c = 0; c < 16; ++c) {
            const float* pc = P + (size_t)(kh*16 + c) * L * L;
            f[c] = wnw*pc[i00] + wne*pc[i01] + wsw*pc[i10] + wse*pc[i11];
        }
        #pragma unroll
        for (int q = 0; q < 2; ++q) {
            s16x8 hi8;
            #pragma unroll
            for (int e = 0; e < 8; ++e) hi8[e] = f2bf_fast(f[q*8+e]);
            int off = pt*128 + ((kh*32 + q*16) ^ ptswz);
            *(s16x8*)(smem + off) = hi8;
        }
        __syncthreads();

        #pragma unroll
        for (int ks = 0; ks < 2; ++ks) {
            s16x8 B[4];
            #pragma unroll
            for (int mt = 0; mt < 4; ++mt)
                B[mt] = *(s16x8*)(smem + (mt*16 + s)*128 + ((ks*64 + g*16) ^ swz));
            #pragma unroll
            for (int j = 0; j < 4; ++j) {
                size_t ro = (size_t)((4*j + w)*16 + s) * 576 + (size_t)(pl*64 + ks*32 + g*8);
                s16x8 Ah = *(const s16x8*)(W1h + ro);
                s16x8 Al = *(const s16x8*)(W1l + ro);
                #pragma unroll
                for (int mt = 0; mt < 4; ++mt) {
                    acc[mt][j] = mm(Ah, B[mt], acc[mt][j]);
                    acc[mt][j] = mm(Al, B[mt], acc[mt][j]);
                }
            }
        }
        __syncthreads();
    }

    #pragma unroll
    for (int j = 0; j < 4; ++j) {
        f32x4 bv = *(const f32x4*)(b1 + (4*j + w)*16 + g*4);
        #pragma unroll
        for (int mt = 0; mt < 4; ++mt) {
            f32x4 a = acc[mt][j];
            s16x4 hq;
            hq[0] = f2bf_fast(sp100(a[0] + bv[0]));
            hq[1] = f2bf_fast(sp100(a[1] + bv[1]));
            hq[2] = f2bf_fast(sp100(a[2] + bv[2]));
            hq[3] = f2bf_fast(sp100(a[3] + bv[3]));
            int off = (mt*16 + s)*512 + ((((4*j + w)*32) + g*8) ^ swz);
            *(s16x4*)(smem + off) = hq;
        }
    }
    #pragma unroll
    for (int mt = 0; mt < 4; ++mt)
        #pragma unroll
        for (int j = 0; j < 4; ++j) acc[mt][j] = fz;
    __syncthreads();

    #pragma unroll 1
    for (int ks = 0; ks < 8; ++ks) {
        s16x8 B[4];
        #pragma unroll
        for (int mt = 0; mt < 4; ++mt)
            B[mt] = *(s16x8*)(smem + (mt*16 + s)*512 + ((ks*64 + g*16) ^ swz));
        #pragma unroll
        for (int j = 0; j < 4; ++j) {
            size_t ro = (size_t)((4*j + w)*16 + s) * 256 + (size_t)(ks*32 + g*8);
            s16x8 Ah = *(const s16x8*)(W2h + ro);
            s16x8 Al = *(const s16x8*)(W2l + ro);
            #pragma unroll
            for (int mt = 0; mt < 4; ++mt) {
                acc[mt][j] = mm(Ah, B[mt], acc[mt][j]);
                acc[mt][j] = mm(Al, B[mt], acc[mt][j]);
            }
        }
    }
    __syncthreads();

    #pragma unroll
    for (int j = 0; j < 4; ++j) {
        f32x4 bv = *(const f32x4*)(b2 + (4*j + w)*16 + g*4);
        #pragma unroll
        for (int mt = 0; mt < 4; ++mt) {
            f32x4 a = acc[mt][j];
            s16x4 hq;
            hq[0] = f2bf_fast(sp100(a[0] + bv[0]));
            hq[1] = f2bf_fast(sp100(a[1] + bv[1]));
            hq[2] = f2bf_fast(sp100(a[2] + bv[2]));
            hq[3] = f2bf_fast(sp100(a[3] + bv[3]));
            int off = (mt*16 + s)*512 + ((((4*j + w)*32) + g*8) ^ swz);
            *(s16x4*)(smem + off) = hq;
        }
    }
    __syncthreads();

    f32x4 acc3[4][2];
    #pragma unroll
    for (int mt = 0; mt < 4; ++mt) { acc3[mt][0] = fz; acc3[mt][1] = fz; }
    #pragma unroll 1
    for (int ks = 0; ks < 8; ++ks) {
        s16x8 B[4];
        #pragma unroll
        for (int mt = 0; mt < 4; ++mt)
            B[mt] = *(s16x8*)(smem + (mt*16 + s)*512 + ((ks*64 + g*16) ^ swz));
        #pragma unroll
        for (int j = 0; j < 2; ++j) {
            size_t ro = (size_t)((4*j + w)*16 + s) * 256 + (size_t)(ks*32 + g*8);
            s16x8 Ah = *(const s16x8*)(Wlh + ro);
            s16x8 Al = *(const s16x8*)(Wll + ro);
            #pragma unroll
            for (int mt = 0; mt < 4; ++mt) {
                acc3[mt][j] = mm(Ah, B[mt], acc3[mt][j]);
                acc3[mt][j] = mm(Al, B[mt], acc3[mt][j]);
            }
        }
    }

    {
        f32x4 bv = *(const f32x4*)(bl + w*16 + g*4);
        #pragma unroll
        for (int mt = 0; mt < 4; ++mt) {
            size_t p = (size_t)(blk*64 + mt*16 + s);
            f32x4 o = acc3[mt][0];
            o[0] += bv[0]; o[1] += bv[1]; o[2] += bv[2]; o[3] += bv[3];
            *(f32x4*)(out + p*64 + (size_t)(w*16 + g*4)) = o;
            if (w == 0 && g == 0)
                out[(size_t)NPTS*64 + p] = acc3[mt][1][0] + bl[64];
        }
    }
}

// ---------------- weight-norm + bf16 hi/lo split (row-major n x k) -------
__global__ __launch_bounds__(64) void prep_weights(
    const float* __restrict__ v1, const float* __restrict__ g1,
    const float* __restrict__ v2, const float* __restrict__ g2,
    const float* __restrict__ vl, const float* __restrict__ gl,
    short* __restrict__ W1h, short* __restrict__ W1l,
    short* __restrict__ W2h, short* __restrict__ W2l,
    short* __restrict__ Wlh, short* __restrict__ Wll)
{
    int i = blockIdx.x, t = threadIdx.x;
    const float* src; float gv; int K; short *dh, *dl; size_t ro;
    if (i < 256)      { src = v1 + (size_t)i*576; gv = g1[i]; K = 576; dh = W1h; dl = W1l; ro = (size_t)i*576; }
    else if (i < 512) { int rr = i-256; src = v2 + (size_t)rr*256; gv = g2[rr]; K = 256; dh = W2h; dl = W2l; ro = (size_t)rr*256; }
    else {
        int rr = i-512;
        K = 256; dh = Wlh; dl = Wll; ro = (size_t)rr*256;
        if (rr >= 65) {
            for (int k = t; k < 256; k += 64) { dh[ro+k] = 0; dl[ro+k] = 0; }
            return;
        }
        src = vl + (size_t)rr*256; gv = gl[rr];
    }
    float ssum = 0.f;
    for (int k = t; k < K; k += 64) { float wv = src[k]; ssum += wv*wv; }
    #pragma unroll
    for (int off = 32; off > 0; off >>= 1) ssum += __shfl_xor(ssum, off, 64);
    float sc = gv / sqrtf(ssum);
    for (int k = t; k < K; k += 64) {
        float wv = src[k] * sc;
        short hb = f2bf(wv);
        dh[ro + k] = hb;
        dl[ro + k] = f2bf(wv - bf2f(hb));
    }
}

extern "C" void kernel_launch(void* const* d_in, const int* in_sizes, int n_in,
                              void* d_out, int out_size, void* d_ws, size_t ws_size,
                              hipStream_t stream)
{
    const float* x = (const float*)d_in[0];
    Planes9 pls;
    for (int i = 0; i < 9; ++i) pls.p[i] = (const float*)d_in[1 + i];
    const float* v1 = (const float*)d_in[10];
    const float* g1 = (const float*)d_in[11];
    const float* b1 = (const float*)d_in[12];
    const float* v2 = (const float*)d_in[13];
    const float* g2 = (const float*)d_in[14];
    const float* b2 = (const float*)d_in[15];
    const float* vl = (const float*)d_in[16];
    const float* gl = (const float*)d_in[17];
    const float* bl = (const float*)d_in[18];

    short* ws16 = (short*)d_ws;
    short* W1h = ws16;                    // 256*576
    short* W1l = ws16 + 147456;
    short* W2h = ws16 + 294912;           // 256*256
    short* W2l = ws16 + 360448;
    short* Wlh = ws16 + 425984;           // 128*256 (padded)
    short* Wll = ws16 + 458752;
    short* tpl = ws16 + 491520;           // bf16 transposed planes: 16515072 shorts
    const size_t w_bytes   = (size_t)491520 * 2;
    const size_t tpl_bytes = (size_t)16515072 * 2;
    int* hist   = (int*)((char*)d_ws + w_bytes + tpl_bytes);
    int* cursor = hist + 4096;
    int* binOf  = cursor + 4096;
    int* perm   = binOf + 131072;
    const size_t need = w_bytes + tpl_bytes + (4096*2 + 131072*2) * sizeof(int);

    prep_weights<<<640, 64, 0, stream>>>(v1, g1, v2, g2, vl, gl,
                                         W1h, W1l, W2h, W2l, Wlh, Wll);

    if (ws_size >= need) {
        transpose_bf16<<<4032, 256, 0, stream>>>(pls, tpl);
        hipError_t e = hipMemsetAsync(hist, 0, 4096 * sizeof(int), stream); (void)e;
        bin_count<<<NPTS / 256, 256, 0, stream>>>(x, hist, binOf);
        scan_bins<<<1, 1024, 0, stream>>>(hist, cursor);
        scatter_pts<<<NPTS / 256, 256, 0, stream>>>(binOf, cursor, perm);
        fused8<<<NPTS / 64, 512, 0, stream>>>(x, tpl, perm,
                                              W1h, W2h, Wlh,
                                              b1, b2, bl, (float*)d_out);
    } else {
        fused3f<<<NPTS / 64, 256, 0, stream>>>(x, pls,
                                               W1h, W1l, W2h, W2l, Wlh, Wll,
                                               b1, b2, bl, (float*)d_out);
    }
}

// Round 14
// 224.900 us; speedup vs baseline: 1.6187x; 1.1724x over previous
//
#include <hip/hip_runtime.h>
#include <hip/hip_bf16.h>
#include <math.h>

#define NPTS 131072

typedef short s16x8 __attribute__((ext_vector_type(8)));
typedef short s16x4 __attribute__((ext_vector_type(4)));
typedef float f32x4 __attribute__((ext_vector_type(4)));
typedef float f32x2 __attribute__((ext_vector_type(2)));
typedef int   i32x4 __attribute__((ext_vector_type(4)));

struct Planes9 { const float* p[9]; };

__device__ __forceinline__ float sp100(float h) {
    float z = 100.0f * h;
    return (fmaxf(z, 0.0f) + log1pf(__expf(-fabsf(z)))) * 0.01f;
}
// branchless softplus on z = 100*h (v_exp/v_log native)
__device__ __forceinline__ float sp100f(float z) {
    float u = __expf(-fabsf(z));
    float l = __logf(1.0f + u);
    return (fmaxf(z, 0.0f) + l) * 0.01f;
}

__device__ __forceinline__ short f2bf(float f) {
    union { float f; unsigned u; } a; a.f = f;
    unsigned u = a.u;
    return (short)((u + 0x7FFFu + ((u >> 16) & 1u)) >> 16);
}
__device__ __forceinline__ float bf2f(short h) {
    union { unsigned u; float f; } a; a.u = ((unsigned)(unsigned short)h) << 16;
    return a.f;
}
__device__ __forceinline__ short f2bf_fast(float f) {
    union { __hip_bfloat16 h; short s; } u;
    u.h = __float2bfloat16(f);
    return u.s;
}
__device__ __forceinline__ f32x2 upk2(unsigned u) {
    union { unsigned v; float f; } a, b;
    a.v = u << 16;
    b.v = u & 0xffff0000u;
    f32x2 r; r[0] = a.f; r[1] = b.f;
    return r;
}

__device__ __forceinline__ f32x4 mm(s16x8 a, s16x8 b, f32x4 c) {
    return __builtin_amdgcn_mfma_f32_16x16x32_bf16(a, b, c, 0, 0, 0);
}

// ======================= point binning: Morton 16x16x16 =======================
__device__ __forceinline__ int spread3(int v) {
    return (v & 1) | ((v & 2) << 2) | ((v & 4) << 4) | ((v & 8) << 6);
}

__global__ __launch_bounds__(256) void bin_count(
    const float* __restrict__ x, int* __restrict__ hist, int* __restrict__ binOf)
{
    int p = blockIdx.x * 256 + threadIdx.x;
    float X = x[3*p+0], Y = x[3*p+1], Z = x[3*p+2];
    int bx = min(max((int)((X + 1.0f) * 8.0f), 0), 15);
    int by = min(max((int)((Y + 1.0f) * 8.0f), 0), 15);
    int bz = min(max((int)((Z + 1.0f) * 8.0f), 0), 15);
    int bin = spread3(bx) | (spread3(by) << 1) | (spread3(bz) << 2);
    binOf[p] = bin;
    atomicAdd(&hist[bin], 1);
}

__global__ __launch_bounds__(1024) void scan_bins(
    const int* __restrict__ hist, int* __restrict__ cursor)
{
    __shared__ int a[1024];
    int t = threadIdx.x;
    int h0 = hist[4*t+0], h1 = hist[4*t+1], h2 = hist[4*t+2], h3 = hist[4*t+3];
    int s = h0 + h1 + h2 + h3;
    a[t] = s;
    __syncthreads();
    #pragma unroll
    for (int off = 1; off < 1024; off <<= 1) {
        int v = a[t];
        if (t >= off) v += a[t - off];
        __syncthreads();
        a[t] = v;
        __syncthreads();
    }
    int base = a[t] - s;
    cursor[4*t+0] = base;
    cursor[4*t+1] = base + h0;
    cursor[4*t+2] = base + h0 + h1;
    cursor[4*t+3] = base + h0 + h1 + h2;
}

__global__ __launch_bounds__(256) void scatter_pts(
    const int* __restrict__ binOf, int* __restrict__ cursor, int* __restrict__ perm)
{
    int p = blockIdx.x * 256 + threadIdx.x;
    int pos = atomicAdd(&cursor[binOf[p]], 1);
    perm[pos] = p;
}

// ---------------- planes (C,H,W) fp32 -> (H,W,C) bf16 ----------------
__global__ __launch_bounds__(256) void transpose_bf16(Planes9 pls, short* __restrict__ dst)
{
    __shared__ float tile[64 * 65];
    int b = blockIdx.x;
    int g = b / 1344, rem = b % 1344;
    int r, t2;
    if (rem < 64)       { r = 0; t2 = rem; }
    else if (rem < 320) { r = 1; t2 = rem - 64; }
    else                { r = 2; t2 = rem - 320; }
    int L = 64 << r;
    int wt = L >> 6;
    int y = t2 / wt, xt = t2 % wt;
    const float* sp = pls.p[g * 3 + r];
    short* dp = dst + (size_t)g * 5505024 + (r == 0 ? 0 : (r == 1 ? 262144 : 1310720));
    int t = threadIdx.x;
    int rowbase = y * L + xt * 64;
    {
        int xi = t & 63, cq = t >> 6;
        #pragma unroll
        for (int cc = 0; cc < 16; ++cc) {
            int c = cq * 16 + cc;
            tile[c * 65 + xi] = sp[(size_t)c * L * L + rowbase + xi];
        }
    }
    __syncthreads();
    {
        int ci = t & 63, xq = t >> 6;
        #pragma unroll
        for (int xx = 0; xx < 16; ++xx) {
            int xcol = xq * 16 + xx;
            dp[(size_t)(rowbase + xcol) * 64 + ci] = f2bf(tile[ci * 65 + xcol]);
        }
    }
}

// per-plane bilerp geometry (bf16 transposed planes); kh in 0..7 -> 8-ch slice
__device__ __forceinline__ void plane_geom(
    int pl, float xc0, float xc1, float xc2, const short* __restrict__ tpl, int kh,
    float& wnw, float& wne, float& wsw, float& wse,
    const short*& pNW, const short*& pNE, const short*& pSW, const short*& pSE)
{
    const int grp = (pl >= 6) ? 2 : (pl >= 3 ? 1 : 0);
    const int r = pl - grp * 3;
    const int L = 64 << r;
    const float u = (grp == 2) ? xc1 : xc0;
    const float v = (grp == 0) ? xc1 : xc2;
    float ix = (u + 1.0f) * 0.5f * (float)(L - 1);
    float iy = (v + 1.0f) * 0.5f * (float)(L - 1);
    float ix0 = floorf(ix), iy0 = floorf(iy);
    float wx = ix - ix0, wy = iy - iy0;
    int x0 = (int)fminf(fmaxf(ix0, 0.f), (float)(L-1));
    int x1 = (int)fminf(fmaxf(ix0+1.f, 0.f), (float)(L-1));
    int y0 = (int)fminf(fmaxf(iy0, 0.f), (float)(L-1));
    int y1 = (int)fminf(fmaxf(iy0+1.f, 0.f), (float)(L-1));
    wnw = (1.f-wx)*(1.f-wy); wne = wx*(1.f-wy); wsw = (1.f-wx)*wy; wse = wx*wy;
    const short* TP = tpl + (size_t)grp * 5505024
                    + (r == 0 ? 0u : (r == 1 ? 262144u : 1310720u));
    pNW = TP + ((size_t)(y0*L + x0) * 64 + kh*8);
    pNE = TP + ((size_t)(y0*L + x1) * 64 + kh*8);
    pSW = TP + ((size_t)(y1*L + x0) * 64 + kh*8);
    pSE = TP + ((size_t)(y1*L + x1) * 64 + kh*8);
}

// ===== fused kernel v10: fused8 + ONLY the (pt,kh)=(t>>3,t&7) remap (coalesced =====
// ===== corner reads: 8 contiguous lanes per point). Geometry per-thread as in v8. =====
__global__ __launch_bounds__(512, 4) void fused10(
    const float* __restrict__ x, const short* __restrict__ tpl,
    const int* __restrict__ perm,
    const short* __restrict__ W1h,
    const short* __restrict__ W2h,
    const short* __restrict__ Wlh,
    const float* __restrict__ b1, const float* __restrict__ b2, const float* __restrict__ bl,
    float* __restrict__ out)
{
    // hB [64 pt][256 k] bf16 (32 KB); L1 feat dbuf 2 x 8 KB aliases its low half
    __shared__ __align__(16) char smem[32768];
    __shared__ float xs[192];
    const int t = threadIdx.x, blk = blockIdx.x;
    if (t < 64) {
        int pi = perm[blk * 64 + t];
        xs[3*t+0] = x[3*pi+0];
        xs[3*t+1] = x[3*pi+1];
        xs[3*t+2] = x[3*pi+2];
    }
    const int w = t >> 6, ln = t & 63, s = ln & 15, g = ln >> 4;
    const int swz = (s & 7) << 4;
    const int pt = t >> 3, kh = t & 7;        // REMAP: 8 consecutive lanes per point
    const int ptswz = (pt & 7) << 4;

    f32x4 acc[4][2];
    const f32x4 fz = {0.f, 0.f, 0.f, 0.f};
    #pragma unroll
    for (int mt = 0; mt < 4; ++mt)
        #pragma unroll
        for (int j = 0; j < 2; ++j) acc[mt][j] = fz;

    __syncthreads();   // xs visible

    const float xc0 = xs[pt*3+0], xc1 = xs[pt*3+1], xc2 = xs[pt*3+2];

    // two named prefetch slots (depth-2 pipeline), static indexing only
    float wA0, wA1, wA2, wA3, wB0, wB1, wB2, wB3;
    i32x4 preA[4], preB[4];
    const short *pNW, *pNE, *pSW, *pSE;

#define ISSUE_A(PL) do { \
        plane_geom(PL, xc0, xc1, xc2, tpl, kh, wA0, wA1, wA2, wA3, pNW, pNE, pSW, pSE); \
        preA[0] = *(const i32x4*)pNW; preA[1] = *(const i32x4*)pNE; \
        preA[2] = *(const i32x4*)pSW; preA[3] = *(const i32x4*)pSE; \
    } while (0)
#define ISSUE_B(PL) do { \
        plane_geom(PL, xc0, xc1, xc2, tpl, kh, wB0, wB1, wB2, wB3, pNW, pNE, pSW, pSE); \
        preB[0] = *(const i32x4*)pNW; preB[1] = *(const i32x4*)pNE; \
        preB[2] = *(const i32x4*)pSW; preB[3] = *(const i32x4*)pSE; \
    } while (0)
#define INTERP(PRE, W0, W1, W2, W3, FB) do { \
        s16x8 hi8; \
        _Pragma("unroll") \
        for (int q = 0; q < 4; ++q) { \
            f32x2 v = upk2((unsigned)PRE[0][q]) * W0 \
                    + upk2((unsigned)PRE[1][q]) * W1 \
                    + upk2((unsigned)PRE[2][q]) * W2 \
                    + upk2((unsigned)PRE[3][q]) * W3; \
            hi8[q*2]   = f2bf_fast(v[0]); \
            hi8[q*2+1] = f2bf_fast(v[1]); \
        } \
        *(s16x8*)((FB) + pt*128 + ((kh*16) ^ ptswz)) = hi8; \
    } while (0)

    ISSUE_A(0);
    ISSUE_B(1);

    // ===== Layer 1: 9 planes, dbuf feat tile, depth-2 prefetch, 1 barrier/plane =====
    #pragma unroll 1
    for (int pl = 0; pl < 9; ++pl) {
        char* fb = smem + ((pl & 1) << 13);
        if (pl & 1) {
            INTERP(preB, wB0, wB1, wB2, wB3, fb);
            if (pl < 7) ISSUE_B(pl + 2);   // 2 MFMA phases + interp to land
        } else {
            INTERP(preA, wA0, wA1, wA2, wA3, fb);
            if (pl < 7) ISSUE_A(pl + 2);
        }
        __syncthreads();

        #pragma unroll
        for (int ks = 0; ks < 2; ++ks) {
            s16x8 B[4];
            #pragma unroll
            for (int mt = 0; mt < 4; ++mt)
                B[mt] = *(s16x8*)(fb + (mt*16 + s)*128 + ((ks*64 + g*16) ^ swz));
            #pragma unroll
            for (int j = 0; j < 2; ++j) {
                size_t ro = (size_t)((8*j + w)*16 + s) * 576 + (size_t)(pl*64 + ks*32 + g*8);
                s16x8 Ah = *(const s16x8*)(W1h + ro);
                #pragma unroll
                for (int mt = 0; mt < 4; ++mt)
                    acc[mt][j] = mm(Ah, B[mt], acc[mt][j]);
            }
        }
    }
#undef ISSUE_A
#undef ISSUE_B
#undef INTERP
    __syncthreads();   // all MFMA reads of feat bufs done before hB overwrite

    // ======== bias + softplus, stage h1 (bf16) to hB [64 pt][256 k] ========
    #pragma unroll
    for (int j = 0; j < 2; ++j) {
        f32x4 bv = *(const f32x4*)(b1 + (8*j + w)*16 + g*4);
        #pragma unroll
        for (int mt = 0; mt < 4; ++mt) {
            f32x4 a = acc[mt][j];
            s16x4 hq;
            hq[0] = f2bf_fast(sp100f((a[0] + bv[0]) * 100.0f));
            hq[1] = f2bf_fast(sp100f((a[1] + bv[1]) * 100.0f));
            hq[2] = f2bf_fast(sp100f((a[2] + bv[2]) * 100.0f));
            hq[3] = f2bf_fast(sp100f((a[3] + bv[3]) * 100.0f));
            int off = (mt*16 + s)*512 + ((((8*j + w)*32) + g*8) ^ swz);
            *(s16x4*)(smem + off) = hq;
        }
    }
    #pragma unroll
    for (int mt = 0; mt < 4; ++mt)
        #pragma unroll
        for (int j = 0; j < 2; ++j) acc[mt][j] = fz;
    __syncthreads();

    // ---------------- Layer 2: K = 256, W-hi only ----------------
    #pragma unroll 1
    for (int ks = 0; ks < 8; ++ks) {
        s16x8 B[4];
        #pragma unroll
        for (int mt = 0; mt < 4; ++mt) {
            int off = (mt*16 + s)*512 + ((ks*64 + g*16) ^ swz);
            B[mt] = *(s16x8*)(smem + off);
        }
        #pragma unroll
        for (int j = 0; j < 2; ++j) {
            size_t ro = (size_t)((8*j + w)*16 + s) * 256 + (size_t)(ks*32 + g*8);
            s16x8 Ah = *(const s16x8*)(W2h + ro);
            #pragma unroll
            for (int mt = 0; mt < 4; ++mt)
                acc[mt][j] = mm(Ah, B[mt], acc[mt][j]);
        }
    }
    __syncthreads();   // all hB reads done before overwrite with h2

    // ======== bias + softplus, stage h2 ========
    #pragma unroll
    for (int j = 0; j < 2; ++j) {
        f32x4 bv = *(const f32x4*)(b2 + (8*j + w)*16 + g*4);
        #pragma unroll
        for (int mt = 0; mt < 4; ++mt) {
            f32x4 a = acc[mt][j];
            s16x4 hq;
            hq[0] = f2bf_fast(sp100f((a[0] + bv[0]) * 100.0f));
            hq[1] = f2bf_fast(sp100f((a[1] + bv[1]) * 100.0f));
            hq[2] = f2bf_fast(sp100f((a[2] + bv[2]) * 100.0f));
            hq[3] = f2bf_fast(sp100f((a[3] + bv[3]) * 100.0f));
            int off = (mt*16 + s)*512 + ((((8*j + w)*32) + g*8) ^ swz);
            *(s16x4*)(smem + off) = hq;
        }
    }
    __syncthreads();

    // ------- Layer 3: Wl padded to 128 rows (8 tiles); wave w owns tile w -------
    f32x4 acc3[4];
    #pragma unroll
    for (int mt = 0; mt < 4; ++mt) acc3[mt] = fz;
    #pragma unroll 1
    for (int ks = 0; ks < 8; ++ks) {
        s16x8 B[4];
        #pragma unroll
        for (int mt = 0; mt < 4; ++mt) {
            int off = (mt*16 + s)*512 + ((ks*64 + g*16) ^ swz);
            B[mt] = *(s16x8*)(smem + off);
        }
        size_t ro = (size_t)(w*16 + s) * 256 + (size_t)(ks*32 + g*8);
        s16x8 Ah = *(const s16x8*)(Wlh + ro);
        #pragma unroll
        for (int mt = 0; mt < 4; ++mt)
            acc3[mt] = mm(Ah, B[mt], acc3[mt]);
    }

    // ---------------- output: feat (P,64) + dsdf (P,1), perm-scattered ----------------
    if (w < 4) {
        f32x4 bv = *(const f32x4*)(bl + w*16 + g*4);
        #pragma unroll
        for (int mt = 0; mt < 4; ++mt) {
            int pl_ = blk*64 + mt*16 + s;
            size_t p = (size_t)perm[pl_];
            f32x4 o = acc3[mt];
            o[0] += bv[0]; o[1] += bv[1]; o[2] += bv[2]; o[3] += bv[3];
            *(f32x4*)(out + p*64 + (size_t)(w*16 + g*4)) = o;
        }
    } else if (w == 4 && g == 0) {
        float bld = bl[64];
        #pragma unroll
        for (int mt = 0; mt < 4; ++mt) {
            int pl_ = blk*64 + mt*16 + s;
            size_t p = (size_t)perm[pl_];
            out[(size_t)NPTS*64 + p] = acc3[mt][0] + bld;
        }
    }
}

// ================= fallback (R6-validated, fp32 planes, identity order, split W) =====
__global__ __launch_bounds__(256, 4) void fused3f(
    const float* __restrict__ x, Planes9 pls,
    const short* __restrict__ W1h, const short* __restrict__ W1l,
    const short* __restrict__ W2h, const short* __restrict__ W2l,
    const short* __restrict__ Wlh, const short* __restrict__ Wll,
    const float* __restrict__ b1, const float* __restrict__ b2, const float* __restrict__ bl,
    float* __restrict__ out)
{
    __shared__ __align__(16) char smem[32768];
    __shared__ float xs[192];
    const int t = threadIdx.x, blk = blockIdx.x;
    if (t < 64) {
        int pi = blk * 64 + t;
        xs[3*t+0] = x[3*pi+0];
        xs[3*t+1] = x[3*pi+1];
        xs[3*t+2] = x[3*pi+2];
    }
    const int w = t >> 6, ln = t & 63, s = ln & 15, g = ln >> 4;
    const int swz = (s & 7) << 4;
    const int pt = t & 63, kh = t >> 6;
    const int ptswz = (pt & 7) << 4;

    f32x4 acc[4][4];
    const f32x4 fz = {0.f, 0.f, 0.f, 0.f};
    #pragma unroll
    for (int mt = 0; mt < 4; ++mt)
        #pragma unroll
        for (int j = 0; j < 4; ++j) acc[mt][j] = fz;
    __syncthreads();

    #pragma unroll 1
    for (int pl = 0; pl < 9; ++pl) {
        const int grp = (pl >= 6) ? 2 : (pl >= 3 ? 1 : 0);
        const int r = pl - grp * 3;
        const int L = 64 << r;
        float u, v;
        { float a0 = xs[pt*3+0], a1 = xs[pt*3+1], a2 = xs[pt*3+2];
          u = (grp == 2) ? a1 : a0;
          v = (grp == 0) ? a1 : a2; }
        float ix = (u + 1.0f) * 0.5f * (float)(L - 1);
        float iy = (v + 1.0f) * 0.5f * (float)(L - 1);
        float ix0 = floorf(ix), iy0 = floorf(iy);
        float wx = ix - ix0, wy = iy - iy0;
        int x0 = (int)fminf(fmaxf(ix0, 0.f), (float)(L-1));
        int x1 = (int)fminf(fmaxf(ix0+1.f, 0.f), (float)(L-1));
        int y0 = (int)fminf(fmaxf(iy0, 0.f), (float)(L-1));
        int y1 = (int)fminf(fmaxf(iy0+1.f, 0.f), (float)(L-1));
        float wnw = (1.f-wx)*(1.f-wy), wne = wx*(1.f-wy), wsw = (1.f-wx)*wy, wse = wx*wy;

        const float* P = pls.p[pl];
        const int i00 = y0*L+x0, i01 = y0*L+x1, i10 = y1*L+x0, i11 = y1*L+x1;
        float f[16];
        #pragma unroll 8
        for (int c = 0; c < 16; ++c) {
            const float* pc = P + (size_t)(kh*16 + c) * L * L;
            f[c] = wnw*pc[i00] + wne*pc[i01] + wsw*pc[i10] + wse*pc[i11];
        }
        #pragma unroll
        for (int q = 0; q < 2; ++q) {
            s16x8 hi8;
            #pragma unroll
            for (int e = 0; e < 8; ++e) hi8[e] = f2bf_fast(f[q*8+e]);
            int off = pt*128 + ((kh*32 + q*16) ^ ptswz);
            *(s16x8*)(smem + off) = hi8;
        }
        __syncthreads();

        #pragma unroll
        for (int ks = 0; ks < 2; ++ks) {
            s16x8 B[4];
            #pragma unroll
            for (int mt = 0; mt < 4; ++mt)
                B[mt] = *(s16x8*)(smem + (mt*16 + s)*128 + ((ks*64 + g*16) ^ swz));
            #pragma unroll
            for (int j = 0; j < 4; ++j) {
                size_t ro = (size_t)((4*j + w)*16 + s) * 576 + (size_t)(pl*64 + ks*32 + g*8);
                s16x8 Ah = *(const s16x8*)(W1h + ro);
                s16x8 Al = *(const s16x8*)(W1l + ro);
                #pragma unroll
                for (int mt = 0; mt < 4; ++mt) {
                    acc[mt][j] = mm(Ah, B[mt], acc[mt][j]);
                    acc[mt][j] = mm(Al, B[mt], acc[mt][j]);
                }
            }
        }
        __syncthreads();
    }

    #pragma unroll
    for (int j = 0; j < 4; ++j) {
        f32x4 bv = *(const f32x4*)(b1 + (4*j + w)*16 + g*4);
        #pragma unroll
        for (int mt = 0; mt < 4; ++mt) {
            f32x4 a = acc[mt][j];
            s16x4 hq;
            hq[0] = f2bf_fast(sp100(a[0] + bv[0]));
            hq[1] = f2bf_fast(sp100(a[1] + bv[1]));
            hq[2] = f2bf_fast(sp100(a[2] + bv[2]));
            hq[3] = f2bf_fast(sp100(a[3] + bv[3]));
            int off = (mt*16 + s)*512 + ((((4*j + w)*32) + g*8) ^ swz);
            *(s16x4*)(smem + off) = hq;
        }
    }
    #pragma unroll
    for (int mt = 0; mt < 4; ++mt)
        #pragma unroll
        for (int j = 0; j < 4; ++j) acc[mt][j] = fz;
    __syncthreads();

    #pragma unroll 1
    for (int ks = 0; ks < 8; ++ks) {
        s16x8 B[4];
        #pragma unroll
        for (int mt = 0; mt < 4; ++mt)
            B[mt] = *(s16x8*)(smem + (mt*16 + s)*512 + ((ks*64 + g*16) ^ swz));
        #pragma unroll
        for (int j = 0; j < 4; ++j) {
            size_t ro = (size_t)((4*j + w)*16 + s) * 256 + (size_t)(ks*32 + g*8);
            s16x8 Ah = *(const s16x8*)(W2h + ro);
            s16x8 Al = *(const s16x8*)(W2l + ro);
            #pragma unroll
            for (int mt = 0; mt < 4; ++mt) {
                acc[mt][j] = mm(Ah, B[mt], acc[mt][j]);
                acc[mt][j] = mm(Al, B[mt], acc[mt][j]);
            }
        }
    }
    __syncthreads();

    #pragma unroll
    for (int j = 0; j < 4; ++j) {
        f32x4 bv = *(const f32x4*)(b2 + (4*j + w)*16 + g*4);
        #pragma unroll
        for (int mt = 0; mt < 4; ++mt) {
            f32x4 a = acc[mt][j];
            s16x4 hq;
            hq[0] = f2bf_fast(sp100(a[0] + bv[0]));
            hq[1] = f2bf_fast(sp100(a[1] + bv[1]));
            hq[2] = f2bf_fast(sp100(a[2] + bv[2]));
            hq[3] = f2bf_fast(sp100(a[3] + bv[3]));
            int off = (mt*16 + s)*512 + ((((4*j + w)*32) + g*8) ^ swz);
            *(s16x4*)(smem + off) = hq;
        }
    }
    __syncthreads();

    f32x4 acc3[4][2];
    #pragma unroll
    for (int mt = 0; mt < 4; ++mt) { acc3[mt][0] = fz; acc3[mt][1] = fz; }
    #pragma unroll 1
    for (int ks = 0; ks < 8; ++ks) {
        s16x8 B[4];
        #pragma unroll
        for (int mt = 0; mt < 4; ++mt)
            B[mt] = *(s16x8*)(smem + (mt*16 + s)*512 + ((ks*64 + g*16) ^ swz));
        #pragma unroll
        for (int j = 0; j < 2; ++j) {
            size_t ro = (size_t)((4*j + w)*16 + s) * 256 + (size_t)(ks*32 + g*8);
            s16x8 Ah = *(const s16x8*)(Wlh + ro);
            s16x8 Al = *(const s16x8*)(Wll + ro);
            #pragma unroll
            for (int mt = 0; mt < 4; ++mt) {
                acc3[mt][j] = mm(Ah, B[mt], acc3[mt][j]);
                acc3[mt][j] = mm(Al, B[mt], acc3[mt][j]);
            }
        }
    }

    {
        f32x4 bv = *(const f32x4*)(bl + w*16 + g*4);
        #pragma unroll
        for (int mt = 0; mt < 4; ++mt) {
            size_t p = (size_t)(blk*64 + mt*16 + s);
            f32x4 o = acc3[mt][0];
            o[0] += bv[0]; o[1] += bv[1]; o[2] += bv[2]; o[3] += bv[3];
            *(f32x4*)(out + p*64 + (size_t)(w*16 + g*4)) = o;
            if (w == 0 && g == 0)
                out[(size_t)NPTS*64 + p] = acc3[mt][1][0] + bl[64];
        }
    }
}

// ---------------- weight-norm + bf16 hi/lo split (row-major n x k) -------
__global__ __launch_bounds__(64) void prep_weights(
    const float* __restrict__ v1, const float* __restrict__ g1,
    const float* __restrict__ v2, const float* __restrict__ g2,
    const float* __restrict__ vl, const float* __restrict__ gl,
    short* __restrict__ W1h, short* __restrict__ W1l,
    short* __restrict__ W2h, short* __restrict__ W2l,
    short* __restrict__ Wlh, short* __restrict__ Wll)
{
    int i = blockIdx.x, t = threadIdx.x;
    const float* src; float gv; int K; short *dh, *dl; size_t ro;
    if (i < 256)      { src = v1 + (size_t)i*576; gv = g1[i]; K = 576; dh = W1h; dl = W1l; ro = (size_t)i*576; }
    else if (i < 512) { int rr = i-256; src = v2 + (size_t)rr*256; gv = g2[rr]; K = 256; dh = W2h; dl = W2l; ro = (size_t)rr*256; }
    else {
        int rr = i-512;
        K = 256; dh = Wlh; dl = Wll; ro = (size_t)rr*256;
        if (rr >= 65) {
            for (int k = t; k < 256; k += 64) { dh[ro+k] = 0; dl[ro+k] = 0; }
            return;
        }
        src = vl + (size_t)rr*256; gv = gl[rr];
    }
    float ssum = 0.f;
    for (int k = t; k < K; k += 64) { float wv = src[k]; ssum += wv*wv; }
    #pragma unroll
    for (int off = 32; off > 0; off >>= 1) ssum += __shfl_xor(ssum, off, 64);
    float sc = gv / sqrtf(ssum);
    for (int k = t; k < K; k += 64) {
        float wv = src[k] * sc;
        short hb = f2bf(wv);
        dh[ro + k] = hb;
        dl[ro + k] = f2bf(wv - bf2f(hb));
    }
}

extern "C" void kernel_launch(void* const* d_in, const int* in_sizes, int n_in,
                              void* d_out, int out_size, void* d_ws, size_t ws_size,
                              hipStream_t stream)
{
    const float* x = (const float*)d_in[0];
    Planes9 pls;
    for (int i = 0; i < 9; ++i) pls.p[i] = (const float*)d_in[1 + i];
    const float* v1 = (const float*)d_in[10];
    const float* g1 = (const float*)d_in[11];
    const float* b1 = (const float*)d_in[12];
    const float* v2 = (const float*)d_in[13];
    const float* g2 = (const float*)d_in[14];
    const float* b2 = (const float*)d_in[15];
    const float* vl = (const float*)d_in[16];
    const float* gl = (const float*)d_in[17];
    const float* bl = (const float*)d_in[18];

    short* ws16 = (short*)d_ws;
    short* W1h = ws16;                    // 256*576
    short* W1l = ws16 + 147456;
    short* W2h = ws16 + 294912;           // 256*256
    short* W2l = ws16 + 360448;
    short* Wlh = ws16 + 425984;           // 128*256 (padded)
    short* Wll = ws16 + 458752;
    short* tpl = ws16 + 491520;           // bf16 transposed planes: 16515072 shorts
    const size_t w_bytes   = (size_t)491520 * 2;
    const size_t tpl_bytes = (size_t)16515072 * 2;
    int* hist   = (int*)((char*)d_ws + w_bytes + tpl_bytes);
    int* cursor = hist + 4096;
    int* binOf  = cursor + 4096;
    int* perm   = binOf + 131072;
    const size_t need = w_bytes + tpl_bytes + (4096*2 + 131072*2) * sizeof(int);

    prep_weights<<<640, 64, 0, stream>>>(v1, g1, v2, g2, vl, gl,
                                         W1h, W1l, W2h, W2l, Wlh, Wll);

    if (ws_size >= need) {
        transpose_bf16<<<4032, 256, 0, stream>>>(pls, tpl);
        hipError_t e = hipMemsetAsync(hist, 0, 4096 * sizeof(int), stream); (void)e;
        bin_count<<<NPTS / 256, 256, 0, stream>>>(x, hist, binOf);
        scan_bins<<<1, 1024, 0, stream>>>(hist, cursor);
        scatter_pts<<<NPTS / 256, 256, 0, stream>>>(binOf, cursor, perm);
        fused10<<<NPTS / 64, 512, 0, stream>>>(x, tpl, perm,
                                               W1h, W2h, Wlh,
                                               b1, b2, bl, (float*)d_out);
    } else {
        fused3f<<<NPTS / 64, 256, 0, stream>>>(x, pls,
                                               W1h, W1l, W2h, W2l, Wlh, Wll,
                                               b1, b2, bl, (float*)d_out);
    }
}

// Round 15
// 223.220 us; speedup vs baseline: 1.6309x; 1.0075x over previous
//
#include <hip/hip_runtime.h>
#include <hip/hip_bf16.h>
#include <math.h>

#define NPTS 131072

typedef short s16x8 __attribute__((ext_vector_type(8)));
typedef short s16x4 __attribute__((ext_vector_type(4)));
typedef float f32x4 __attribute__((ext_vector_type(4)));
typedef float f32x2 __attribute__((ext_vector_type(2)));
typedef int   i32x4 __attribute__((ext_vector_type(4)));

struct Planes9 { const float* p[9]; };

__device__ __forceinline__ float sp100(float h) {
    float z = 100.0f * h;
    return (fmaxf(z, 0.0f) + log1pf(__expf(-fabsf(z)))) * 0.01f;
}
// branchless softplus on z = 100*h (v_exp/v_log native)
__device__ __forceinline__ float sp100f(float z) {
    float u = __expf(-fabsf(z));
    float l = __logf(1.0f + u);
    return (fmaxf(z, 0.0f) + l) * 0.01f;
}

__device__ __forceinline__ short f2bf(float f) {
    union { float f; unsigned u; } a; a.f = f;
    unsigned u = a.u;
    return (short)((u + 0x7FFFu + ((u >> 16) & 1u)) >> 16);
}
__device__ __forceinline__ float bf2f(short h) {
    union { unsigned u; float f; } a; a.u = ((unsigned)(unsigned short)h) << 16;
    return a.f;
}
__device__ __forceinline__ short f2bf_fast(float f) {
    union { __hip_bfloat16 h; short s; } u;
    u.h = __float2bfloat16(f);
    return u.s;
}
__device__ __forceinline__ f32x2 upk2(unsigned u) {
    union { unsigned v; float f; } a, b;
    a.v = u << 16;
    b.v = u & 0xffff0000u;
    f32x2 r; r[0] = a.f; r[1] = b.f;
    return r;
}

__device__ __forceinline__ f32x4 mm(s16x8 a, s16x8 b, f32x4 c) {
    return __builtin_amdgcn_mfma_f32_16x16x32_bf16(a, b, c, 0, 0, 0);
}

// ======================= point binning: Morton 16x16x16 =======================
__device__ __forceinline__ int spread3(int v) {
    return (v & 1) | ((v & 2) << 2) | ((v & 4) << 4) | ((v & 8) << 6);
}

__global__ __launch_bounds__(256) void bin_count(
    const float* __restrict__ x, int* __restrict__ hist, int* __restrict__ binOf)
{
    int p = blockIdx.x * 256 + threadIdx.x;
    float X = x[3*p+0], Y = x[3*p+1], Z = x[3*p+2];
    int bx = min(max((int)((X + 1.0f) * 8.0f), 0), 15);
    int by = min(max((int)((Y + 1.0f) * 8.0f), 0), 15);
    int bz = min(max((int)((Z + 1.0f) * 8.0f), 0), 15);
    int bin = spread3(bx) | (spread3(by) << 1) | (spread3(bz) << 2);
    binOf[p] = bin;
    atomicAdd(&hist[bin], 1);
}

__global__ __launch_bounds__(1024) void scan_bins(
    const int* __restrict__ hist, int* __restrict__ cursor)
{
    __shared__ int a[1024];
    int t = threadIdx.x;
    int h0 = hist[4*t+0], h1 = hist[4*t+1], h2 = hist[4*t+2], h3 = hist[4*t+3];
    int s = h0 + h1 + h2 + h3;
    a[t] = s;
    __syncthreads();
    #pragma unroll
    for (int off = 1; off < 1024; off <<= 1) {
        int v = a[t];
        if (t >= off) v += a[t - off];
        __syncthreads();
        a[t] = v;
        __syncthreads();
    }
    int base = a[t] - s;
    cursor[4*t+0] = base;
    cursor[4*t+1] = base + h0;
    cursor[4*t+2] = base + h0 + h1;
    cursor[4*t+3] = base + h0 + h1 + h2;
}

__global__ __launch_bounds__(256) void scatter_pts(
    const int* __restrict__ binOf, int* __restrict__ cursor, int* __restrict__ perm)
{
    int p = blockIdx.x * 256 + threadIdx.x;
    int pos = atomicAdd(&cursor[binOf[p]], 1);
    perm[pos] = p;
}

// ---------------- planes (C,H,W) fp32 -> (H,W,C) bf16 ----------------
__global__ __launch_bounds__(256) void transpose_bf16(Planes9 pls, short* __restrict__ dst)
{
    __shared__ float tile[64 * 65];
    int b = blockIdx.x;
    int g = b / 1344, rem = b % 1344;
    int r, t2;
    if (rem < 64)       { r = 0; t2 = rem; }
    else if (rem < 320) { r = 1; t2 = rem - 64; }
    else                { r = 2; t2 = rem - 320; }
    int L = 64 << r;
    int wt = L >> 6;
    int y = t2 / wt, xt = t2 % wt;
    const float* sp = pls.p[g * 3 + r];
    short* dp = dst + (size_t)g * 5505024 + (r == 0 ? 0 : (r == 1 ? 262144 : 1310720));
    int t = threadIdx.x;
    int rowbase = y * L + xt * 64;
    {
        int xi = t & 63, cq = t >> 6;
        #pragma unroll
        for (int cc = 0; cc < 16; ++cc) {
            int c = cq * 16 + cc;
            tile[c * 65 + xi] = sp[(size_t)c * L * L + rowbase + xi];
        }
    }
    __syncthreads();
    {
        int ci = t & 63, xq = t >> 6;
        #pragma unroll
        for (int xx = 0; xx < 16; ++xx) {
            int xcol = xq * 16 + xx;
            dp[(size_t)(rowbase + xcol) * 64 + ci] = f2bf(tile[ci * 65 + xcol]);
        }
    }
}

// per-plane bilerp geometry (bf16 transposed planes); kh in 0..7 -> 8-ch slice
__device__ __forceinline__ void plane_geom(
    int pl, float xc0, float xc1, float xc2, const short* __restrict__ tpl, int kh,
    float& wnw, float& wne, float& wsw, float& wse,
    const short*& pNW, const short*& pNE, const short*& pSW, const short*& pSE)
{
    const int grp = (pl >= 6) ? 2 : (pl >= 3 ? 1 : 0);
    const int r = pl - grp * 3;
    const int L = 64 << r;
    const float u = (grp == 2) ? xc1 : xc0;
    const float v = (grp == 0) ? xc1 : xc2;
    float ix = (u + 1.0f) * 0.5f * (float)(L - 1);
    float iy = (v + 1.0f) * 0.5f * (float)(L - 1);
    float ix0 = floorf(ix), iy0 = floorf(iy);
    float wx = ix - ix0, wy = iy - iy0;
    int x0 = (int)fminf(fmaxf(ix0, 0.f), (float)(L-1));
    int x1 = (int)fminf(fmaxf(ix0+1.f, 0.f), (float)(L-1));
    int y0 = (int)fminf(fmaxf(iy0, 0.f), (float)(L-1));
    int y1 = (int)fminf(fmaxf(iy0+1.f, 0.f), (float)(L-1));
    wnw = (1.f-wx)*(1.f-wy); wne = wx*(1.f-wy); wsw = (1.f-wx)*wy; wse = wx*wy;
    const short* TP = tpl + (size_t)grp * 5505024
                    + (r == 0 ? 0u : (r == 1 ? 262144u : 1310720u));
    pNW = TP + ((size_t)(y0*L + x0) * 64 + kh*8);
    pNE = TP + ((size_t)(y0*L + x1) * 64 + kh*8);
    pSW = TP + ((size_t)(y1*L + x0) * 64 + kh*8);
    pSE = TP + ((size_t)(y1*L + x1) * 64 + kh*8);
}

// ===== fused kernel v11: fused10 + XCD-aware block swizzle (T1). Blocks are =====
// ===== Morton-ordered; give each XCD a contiguous 256-block range for L2 reuse. =====
__global__ __launch_bounds__(512, 4) void fused11(
    const float* __restrict__ x, const short* __restrict__ tpl,
    const int* __restrict__ perm,
    const short* __restrict__ W1h,
    const short* __restrict__ W2h,
    const short* __restrict__ Wlh,
    const float* __restrict__ b1, const float* __restrict__ b2, const float* __restrict__ bl,
    float* __restrict__ out)
{
    // hB [64 pt][256 k] bf16 (32 KB); L1 feat dbuf 2 x 8 KB aliases its low half
    __shared__ __align__(16) char smem[32768];
    __shared__ float xs[192];
    const int t = threadIdx.x;
    // XCD swizzle: hw blockIdx b -> data block (b%8)*256 + b/8  (2048 = 8 * 256, bijective)
    const int blk = ((blockIdx.x & 7) << 8) | (blockIdx.x >> 3);
    if (t < 64) {
        int pi = perm[blk * 64 + t];
        xs[3*t+0] = x[3*pi+0];
        xs[3*t+1] = x[3*pi+1];
        xs[3*t+2] = x[3*pi+2];
    }
    const int w = t >> 6, ln = t & 63, s = ln & 15, g = ln >> 4;
    const int swz = (s & 7) << 4;
    const int pt = t >> 3, kh = t & 7;        // 8 consecutive lanes per point
    const int ptswz = (pt & 7) << 4;

    f32x4 acc[4][2];
    const f32x4 fz = {0.f, 0.f, 0.f, 0.f};
    #pragma unroll
    for (int mt = 0; mt < 4; ++mt)
        #pragma unroll
        for (int j = 0; j < 2; ++j) acc[mt][j] = fz;

    __syncthreads();   // xs visible

    const float xc0 = xs[pt*3+0], xc1 = xs[pt*3+1], xc2 = xs[pt*3+2];

    // two named prefetch slots (depth-2 pipeline), static indexing only
    float wA0, wA1, wA2, wA3, wB0, wB1, wB2, wB3;
    i32x4 preA[4], preB[4];
    const short *pNW, *pNE, *pSW, *pSE;

#define ISSUE_A(PL) do { \
        plane_geom(PL, xc0, xc1, xc2, tpl, kh, wA0, wA1, wA2, wA3, pNW, pNE, pSW, pSE); \
        preA[0] = *(const i32x4*)pNW; preA[1] = *(const i32x4*)pNE; \
        preA[2] = *(const i32x4*)pSW; preA[3] = *(const i32x4*)pSE; \
    } while (0)
#define ISSUE_B(PL) do { \
        plane_geom(PL, xc0, xc1, xc2, tpl, kh, wB0, wB1, wB2, wB3, pNW, pNE, pSW, pSE); \
        preB[0] = *(const i32x4*)pNW; preB[1] = *(const i32x4*)pNE; \
        preB[2] = *(const i32x4*)pSW; preB[3] = *(const i32x4*)pSE; \
    } while (0)
#define INTERP(PRE, W0, W1, W2, W3, FB) do { \
        s16x8 hi8; \
        _Pragma("unroll") \
        for (int q = 0; q < 4; ++q) { \
            f32x2 v = upk2((unsigned)PRE[0][q]) * W0 \
                    + upk2((unsigned)PRE[1][q]) * W1 \
                    + upk2((unsigned)PRE[2][q]) * W2 \
                    + upk2((unsigned)PRE[3][q]) * W3; \
            hi8[q*2]   = f2bf_fast(v[0]); \
            hi8[q*2+1] = f2bf_fast(v[1]); \
        } \
        *(s16x8*)((FB) + pt*128 + ((kh*16) ^ ptswz)) = hi8; \
    } while (0)

    ISSUE_A(0);
    ISSUE_B(1);

    // ===== Layer 1: 9 planes, dbuf feat tile, depth-2 prefetch, 1 barrier/plane =====
    #pragma unroll 1
    for (int pl = 0; pl < 9; ++pl) {
        char* fb = smem + ((pl & 1) << 13);
        if (pl & 1) {
            INTERP(preB, wB0, wB1, wB2, wB3, fb);
            if (pl < 7) ISSUE_B(pl + 2);   // 2 MFMA phases + interp to land
        } else {
            INTERP(preA, wA0, wA1, wA2, wA3, fb);
            if (pl < 7) ISSUE_A(pl + 2);
        }
        __syncthreads();

        #pragma unroll
        for (int ks = 0; ks < 2; ++ks) {
            s16x8 B[4];
            #pragma unroll
            for (int mt = 0; mt < 4; ++mt)
                B[mt] = *(s16x8*)(fb + (mt*16 + s)*128 + ((ks*64 + g*16) ^ swz));
            #pragma unroll
            for (int j = 0; j < 2; ++j) {
                size_t ro = (size_t)((8*j + w)*16 + s) * 576 + (size_t)(pl*64 + ks*32 + g*8);
                s16x8 Ah = *(const s16x8*)(W1h + ro);
                #pragma unroll
                for (int mt = 0; mt < 4; ++mt)
                    acc[mt][j] = mm(Ah, B[mt], acc[mt][j]);
            }
        }
    }
#undef ISSUE_A
#undef ISSUE_B
#undef INTERP
    __syncthreads();   // all MFMA reads of feat bufs done before hB overwrite

    // ======== bias + softplus, stage h1 (bf16) to hB [64 pt][256 k] ========
    #pragma unroll
    for (int j = 0; j < 2; ++j) {
        f32x4 bv = *(const f32x4*)(b1 + (8*j + w)*16 + g*4);
        #pragma unroll
        for (int mt = 0; mt < 4; ++mt) {
            f32x4 a = acc[mt][j];
            s16x4 hq;
            hq[0] = f2bf_fast(sp100f((a[0] + bv[0]) * 100.0f));
            hq[1] = f2bf_fast(sp100f((a[1] + bv[1]) * 100.0f));
            hq[2] = f2bf_fast(sp100f((a[2] + bv[2]) * 100.0f));
            hq[3] = f2bf_fast(sp100f((a[3] + bv[3]) * 100.0f));
            int off = (mt*16 + s)*512 + ((((8*j + w)*32) + g*8) ^ swz);
            *(s16x4*)(smem + off) = hq;
        }
    }
    #pragma unroll
    for (int mt = 0; mt < 4; ++mt)
        #pragma unroll
        for (int j = 0; j < 2; ++j) acc[mt][j] = fz;
    __syncthreads();

    // ---------------- Layer 2: K = 256, W-hi only ----------------
    #pragma unroll 1
    for (int ks = 0; ks < 8; ++ks) {
        s16x8 B[4];
        #pragma unroll
        for (int mt = 0; mt < 4; ++mt) {
            int off = (mt*16 + s)*512 + ((ks*64 + g*16) ^ swz);
            B[mt] = *(s16x8*)(smem + off);
        }
        #pragma unroll
        for (int j = 0; j < 2; ++j) {
            size_t ro = (size_t)((8*j + w)*16 + s) * 256 + (size_t)(ks*32 + g*8);
            s16x8 Ah = *(const s16x8*)(W2h + ro);
            #pragma unroll
            for (int mt = 0; mt < 4; ++mt)
                acc[mt][j] = mm(Ah, B[mt], acc[mt][j]);
        }
    }
    __syncthreads();   // all hB reads done before overwrite with h2

    // ======== bias + softplus, stage h2 ========
    #pragma unroll
    for (int j = 0; j < 2; ++j) {
        f32x4 bv = *(const f32x4*)(b2 + (8*j + w)*16 + g*4);
        #pragma unroll
        for (int mt = 0; mt < 4; ++mt) {
            f32x4 a = acc[mt][j];
            s16x4 hq;
            hq[0] = f2bf_fast(sp100f((a[0] + bv[0]) * 100.0f));
            hq[1] = f2bf_fast(sp100f((a[1] + bv[1]) * 100.0f));
            hq[2] = f2bf_fast(sp100f((a[2] + bv[2]) * 100.0f));
            hq[3] = f2bf_fast(sp100f((a[3] + bv[3]) * 100.0f));
            int off = (mt*16 + s)*512 + ((((8*j + w)*32) + g*8) ^ swz);
            *(s16x4*)(smem + off) = hq;
        }
    }
    __syncthreads();

    // ------- Layer 3: Wl padded to 128 rows (8 tiles); wave w owns tile w -------
    f32x4 acc3[4];
    #pragma unroll
    for (int mt = 0; mt < 4; ++mt) acc3[mt] = fz;
    #pragma unroll 1
    for (int ks = 0; ks < 8; ++ks) {
        s16x8 B[4];
        #pragma unroll
        for (int mt = 0; mt < 4; ++mt) {
            int off = (mt*16 + s)*512 + ((ks*64 + g*16) ^ swz);
            B[mt] = *(s16x8*)(smem + off);
        }
        size_t ro = (size_t)(w*16 + s) * 256 + (size_t)(ks*32 + g*8);
        s16x8 Ah = *(const s16x8*)(Wlh + ro);
        #pragma unroll
        for (int mt = 0; mt < 4; ++mt)
            acc3[mt] = mm(Ah, B[mt], acc3[mt]);
    }

    // ---------------- output: feat (P,64) + dsdf (P,1), perm-scattered ----------------
    if (w < 4) {
        f32x4 bv = *(const f32x4*)(bl + w*16 + g*4);
        #pragma unroll
        for (int mt = 0; mt < 4; ++mt) {
            int pl_ = blk*64 + mt*16 + s;
            size_t p = (size_t)perm[pl_];
            f32x4 o = acc3[mt];
            o[0] += bv[0]; o[1] += bv[1]; o[2] += bv[2]; o[3] += bv[3];
            *(f32x4*)(out + p*64 + (size_t)(w*16 + g*4)) = o;
        }
    } else if (w == 4 && g == 0) {
        float bld = bl[64];
        #pragma unroll
        for (int mt = 0; mt < 4; ++mt) {
            int pl_ = blk*64 + mt*16 + s;
            size_t p = (size_t)perm[pl_];
            out[(size_t)NPTS*64 + p] = acc3[mt][0] + bld;
        }
    }
}

// ================= fallback (R6-validated, fp32 planes, identity order, split W) =====
__global__ __launch_bounds__(256, 4) void fused3f(
    const float* __restrict__ x, Planes9 pls,
    const short* __restrict__ W1h, const short* __restrict__ W1l,
    const short* __restrict__ W2h, const short* __restrict__ W2l,
    const short* __restrict__ Wlh, const short* __restrict__ Wll,
    const float* __restrict__ b1, const float* __restrict__ b2, const float* __restrict__ bl,
    float* __restrict__ out)
{
    __shared__ __align__(16) char smem[32768];
    __shared__ float xs[192];
    const int t = threadIdx.x, blk = blockIdx.x;
    if (t < 64) {
        int pi = blk * 64 + t;
        xs[3*t+0] = x[3*pi+0];
        xs[3*t+1] = x[3*pi+1];
        xs[3*t+2] = x[3*pi+2];
    }
    const int w = t >> 6, ln = t & 63, s = ln & 15, g = ln >> 4;
    const int swz = (s & 7) << 4;
    const int pt = t & 63, kh = t >> 6;
    const int ptswz = (pt & 7) << 4;

    f32x4 acc[4][4];
    const f32x4 fz = {0.f, 0.f, 0.f, 0.f};
    #pragma unroll
    for (int mt = 0; mt < 4; ++mt)
        #pragma unroll
        for (int j = 0; j < 4; ++j) acc[mt][j] = fz;
    __syncthreads();

    #pragma unroll 1
    for (int pl = 0; pl < 9; ++pl) {
        const int grp = (pl >= 6) ? 2 : (pl >= 3 ? 1 : 0);
        const int r = pl - grp * 3;
        const int L = 64 << r;
        float u, v;
        { float a0 = xs[pt*3+0], a1 = xs[pt*3+1], a2 = xs[pt*3+2];
          u = (grp == 2) ? a1 : a0;
          v = (grp == 0) ? a1 : a2; }
        float ix = (u + 1.0f) * 0.5f * (float)(L - 1);
        float iy = (v + 1.0f) * 0.5f * (float)(L - 1);
        float ix0 = floorf(ix), iy0 = floorf(iy);
        float wx = ix - ix0, wy = iy - iy0;
        int x0 = (int)fminf(fmaxf(ix0, 0.f), (float)(L-1));
        int x1 = (int)fminf(fmaxf(ix0+1.f, 0.f), (float)(L-1));
        int y0 = (int)fminf(fmaxf(iy0, 0.f), (float)(L-1));
        int y1 = (int)fminf(fmaxf(iy0+1.f, 0.f), (float)(L-1));
        float wnw = (1.f-wx)*(1.f-wy), wne = wx*(1.f-wy), wsw = (1.f-wx)*wy, wse = wx*wy;

        const float* P = pls.p[pl];
        const int i00 = y0*L+x0, i01 = y0*L+x1, i10 = y1*L+x0, i11 = y1*L+x1;
        float f[16];
        #pragma unroll 8
        for (int c = 0; c < 16; ++c) {
            const float* pc = P + (size_t)(kh*16 + c) * L * L;
            f[c] = wnw*pc[i00] + wne*pc[i01] + wsw*pc[i10] + wse*pc[i11];
        }
        #pragma unroll
        for (int q = 0; q < 2; ++q) {
            s16x8 hi8;
            #pragma unroll
            for (int e = 0; e < 8; ++e) hi8[e] = f2bf_fast(f[q*8+e]);
            int off = pt*128 + ((kh*32 + q*16) ^ ptswz);
            *(s16x8*)(smem + off) = hi8;
        }
        __syncthreads();

        #pragma unroll
        for (int ks = 0; ks < 2; ++ks) {
            s16x8 B[4];
            #pragma unroll
            for (int mt = 0; mt < 4; ++mt)
                B[mt] = *(s16x8*)(smem + (mt*16 + s)*128 + ((ks*64 + g*16) ^ swz));
            #pragma unroll
            for (int j = 0; j < 4; ++j) {
                size_t ro = (size_t)((4*j + w)*16 + s) * 576 + (size_t)(pl*64 + ks*32 + g*8);
                s16x8 Ah = *(const s16x8*)(W1h + ro);
                s16x8 Al = *(const s16x8*)(W1l + ro);
                #pragma unroll
                for (int mt = 0; mt < 4; ++mt) {
                    acc[mt][j] = mm(Ah, B[mt], acc[mt][j]);
                    acc[mt][j] = mm(Al, B[mt], acc[mt][j]);
                }
            }
        }
        __syncthreads();
    }

    #pragma unroll
    for (int j = 0; j < 4; ++j) {
        f32x4 bv = *(const f32x4*)(b1 + (4*j + w)*16 + g*4);
        #pragma unroll
        for (int mt = 0; mt < 4; ++mt) {
            f32x4 a = acc[mt][j];
            s16x4 hq;
            hq[0] = f2bf_fast(sp100(a[0] + bv[0]));
            hq[1] = f2bf_fast(sp100(a[1] + bv[1]));
            hq[2] = f2bf_fast(sp100(a[2] + bv[2]));
            hq[3] = f2bf_fast(sp100(a[3] + bv[3]));
            int off = (mt*16 + s)*512 + ((((4*j + w)*32) + g*8) ^ swz);
            *(s16x4*)(smem + off) = hq;
        }
    }
    #pragma unroll
    for (int mt = 0; mt < 4; ++mt)
        #pragma unroll
        for (int j = 0; j < 4; ++j) acc[mt][j] = fz;
    __syncthreads();

    #pragma unroll 1
    for (int ks = 0; ks < 8; ++ks) {
        s16x8 B[4];
        #pragma unroll
        for (int mt = 0; mt < 4; ++mt)
            B[mt] = *(s16x8*)(smem + (mt*16 + s)*512 + ((ks*64 + g*16) ^ swz));
        #pragma unroll
        for (int j = 0; j < 4; ++j) {
            size_t ro = (size_t)((4*j + w)*16 + s) * 256 + (size_t)(ks*32 + g*8);
            s16x8 Ah = *(const s16x8*)(W2h + ro);
            s16x8 Al = *(const s16x8*)(W2l + ro);
            #pragma unroll
            for (int mt = 0; mt < 4; ++mt) {
                acc[mt][j] = mm(Ah, B[mt], acc[mt][j]);
                acc[mt][j] = mm(Al, B[mt], acc[mt][j]);
            }
        }
    }
    __syncthreads();

    #pragma unroll
    for (int j = 0; j < 4; ++j) {
        f32x4 bv = *(const f32x4*)(b2 + (4*j + w)*16 + g*4);
        #pragma unroll
        for (int mt = 0; mt < 4; ++mt) {
            f32x4 a = acc[mt][j];
            s16x4 hq;
            hq[0] = f2bf_fast(sp100(a[0] + bv[0]));
            hq[1] = f2bf_fast(sp100(a[1] + bv[1]));
            hq[2] = f2bf_fast(sp100(a[2] + bv[2]));
            hq[3] = f2bf_fast(sp100(a[3] + bv[3]));
            int off = (mt*16 + s)*512 + ((((4*j + w)*32) + g*8) ^ swz);
            *(s16x4*)(smem + off) = hq;
        }
    }
    __syncthreads();

    f32x4 acc3[4][2];
    #pragma unroll
    for (int mt = 0; mt < 4; ++mt) { acc3[mt][0] = fz; acc3[mt][1] = fz; }
    #pragma unroll 1
    for (int ks = 0; ks < 8; ++ks) {
        s16x8 B[4];
        #pragma unroll
        for (int mt = 0; mt < 4; ++mt)
            B[mt] = *(s16x8*)(smem + (mt*16 + s)*512 + ((ks*64 + g*16) ^ swz));
        #pragma unroll
        for (int j = 0; j < 2; ++j) {
            size_t ro = (size_t)((4*j + w)*16 + s) * 256 + (size_t)(ks*32 + g*8);
            s16x8 Ah = *(const s16x8*)(Wlh + ro);
            s16x8 Al = *(const s16x8*)(Wll + ro);
            #pragma unroll
            for (int mt = 0; mt < 4; ++mt) {
                acc3[mt][j] = mm(Ah, B[mt], acc3[mt][j]);
                acc3[mt][j] = mm(Al, B[mt], acc3[mt][j]);
            }
        }
    }

    {
        f32x4 bv = *(const f32x4*)(bl + w*16 + g*4);
        #pragma unroll
        for (int mt = 0; mt < 4; ++mt) {
            size_t p = (size_t)(blk*64 + mt*16 + s);
            f32x4 o = acc3[mt][0];
            o[0] += bv[0]; o[1] += bv[1]; o[2] += bv[2]; o[3] += bv[3];
            *(f32x4*)(out + p*64 + (size_t)(w*16 + g*4)) = o;
            if (w == 0 && g == 0)
                out[(size_t)NPTS*64 + p] = acc3[mt][1][0] + bl[64];
        }
    }
}

// ---------------- weight-norm + bf16 hi/lo split (row-major n x k) -------
__global__ __launch_bounds__(64) void prep_weights(
    const float* __restrict__ v1, const float* __restrict__ g1,
    const float* __restrict__ v2, const float* __restrict__ g2,
    const float* __restrict__ vl, const float* __restrict__ gl,
    short* __restrict__ W1h, short* __restrict__ W1l,
    short* __restrict__ W2h, short* __restrict__ W2l,
    short* __restrict__ Wlh, short* __restrict__ Wll)
{
    int i = blockIdx.x, t = threadIdx.x;
    const float* src; float gv; int K; short *dh, *dl; size_t ro;
    if (i < 256)      { src = v1 + (size_t)i*576; gv = g1[i]; K = 576; dh = W1h; dl = W1l; ro = (size_t)i*576; }
    else if (i < 512) { int rr = i-256; src = v2 + (size_t)rr*256; gv = g2[rr]; K = 256; dh = W2h; dl = W2l; ro = (size_t)rr*256; }
    else {
        int rr = i-512;
        K = 256; dh = Wlh; dl = Wll; ro = (size_t)rr*256;
        if (rr >= 65) {
            for (int k = t; k < 256; k += 64) { dh[ro+k] = 0; dl[ro+k] = 0; }
            return;
        }
        src = vl + (size_t)rr*256; gv = gl[rr];
    }
    float ssum = 0.f;
    for (int k = t; k < K; k += 64) { float wv = src[k]; ssum += wv*wv; }
    #pragma unroll
    for (int off = 32; off > 0; off >>= 1) ssum += __shfl_xor(ssum, off, 64);
    float sc = gv / sqrtf(ssum);
    for (int k = t; k < K; k += 64) {
        float wv = src[k] * sc;
        short hb = f2bf(wv);
        dh[ro + k] = hb;
        dl[ro + k] = f2bf(wv - bf2f(hb));
    }
}

extern "C" void kernel_launch(void* const* d_in, const int* in_sizes, int n_in,
                              void* d_out, int out_size, void* d_ws, size_t ws_size,
                              hipStream_t stream)
{
    const float* x = (const float*)d_in[0];
    Planes9 pls;
    for (int i = 0; i < 9; ++i) pls.p[i] = (const float*)d_in[1 + i];
    const float* v1 = (const float*)d_in[10];
    const float* g1 = (const float*)d_in[11];
    const float* b1 = (const float*)d_in[12];
    const float* v2 = (const float*)d_in[13];
    const float* g2 = (const float*)d_in[14];
    const float* b2 = (const float*)d_in[15];
    const float* vl = (const float*)d_in[16];
    const float* gl = (const float*)d_in[17];
    const float* bl = (const float*)d_in[18];

    short* ws16 = (short*)d_ws;
    short* W1h = ws16;                    // 256*576
    short* W1l = ws16 + 147456;
    short* W2h = ws16 + 294912;           // 256*256
    short* W2l = ws16 + 360448;
    short* Wlh = ws16 + 425984;           // 128*256 (padded)
    short* Wll = ws16 + 458752;
    short* tpl = ws16 + 491520;           // bf16 transposed planes: 16515072 shorts
    const size_t w_bytes   = (size_t)491520 * 2;
    const size_t tpl_bytes = (size_t)16515072 * 2;
    int* hist   = (int*)((char*)d_ws + w_bytes + tpl_bytes);
    int* cursor = hist + 4096;
    int* binOf  = cursor + 4096;
    int* perm   = binOf + 131072;
    const size_t need = w_bytes + tpl_bytes + (4096*2 + 131072*2) * sizeof(int);

    prep_weights<<<640, 64, 0, stream>>>(v1, g1, v2, g2, vl, gl,
                                         W1h, W1l, W2h, W2l, Wlh, Wll);

    if (ws_size >= need) {
        transpose_bf16<<<4032, 256, 0, stream>>>(pls, tpl);
        hipError_t e = hipMemsetAsync(hist, 0, 4096 * sizeof(int), stream); (void)e;
        bin_count<<<NPTS / 256, 256, 0, stream>>>(x, hist, binOf);
        scan_bins<<<1, 1024, 0, stream>>>(hist, cursor);
        scatter_pts<<<NPTS / 256, 256, 0, stream>>>(binOf, cursor, perm);
        fused11<<<NPTS / 64, 512, 0, stream>>>(x, tpl, perm,
                                               W1h, W2h, Wlh,
                                               b1, b2, bl, (float*)d_out);
    } else {
        fused3f<<<NPTS / 64, 256, 0, stream>>>(x, pls,
                                               W1h, W1l, W2h, W2l, Wlh, Wll,
                                               b1, b2, bl, (float*)d_out);
    }
}

// Round 16
// 222.680 us; speedup vs baseline: 1.6349x; 1.0024x over previous
//
#include <hip/hip_runtime.h>
#include <hip/hip_bf16.h>
#include <math.h>

#define NPTS 131072

typedef short s16x8 __attribute__((ext_vector_type(8)));
typedef short s16x4 __attribute__((ext_vector_type(4)));
typedef float f32x4 __attribute__((ext_vector_type(4)));
typedef float f32x2 __attribute__((ext_vector_type(2)));
typedef int   i32x4 __attribute__((ext_vector_type(4)));

struct Planes9 { const float* p[9]; };

__device__ __forceinline__ float sp100(float h) {
    float z = 100.0f * h;
    return (fmaxf(z, 0.0f) + log1pf(__expf(-fabsf(z)))) * 0.01f;
}
// branchless softplus on z = 100*h (v_exp/v_log native)
__device__ __forceinline__ float sp100f(float z) {
    float u = __expf(-fabsf(z));
    float l = __logf(1.0f + u);
    return (fmaxf(z, 0.0f) + l) * 0.01f;
}

__device__ __forceinline__ short f2bf(float f) {
    union { float f; unsigned u; } a; a.f = f;
    unsigned u = a.u;
    return (short)((u + 0x7FFFu + ((u >> 16) & 1u)) >> 16);
}
__device__ __forceinline__ float bf2f(short h) {
    union { unsigned u; float f; } a; a.u = ((unsigned)(unsigned short)h) << 16;
    return a.f;
}
__device__ __forceinline__ short f2bf_fast(float f) {
    union { __hip_bfloat16 h; short s; } u;
    u.h = __float2bfloat16(f);
    return u.s;
}
__device__ __forceinline__ f32x2 upk2(unsigned u) {
    union { unsigned v; float f; } a, b;
    a.v = u << 16;
    b.v = u & 0xffff0000u;
    f32x2 r; r[0] = a.f; r[1] = b.f;
    return r;
}

__device__ __forceinline__ f32x4 mm(s16x8 a, s16x8 b, f32x4 c) {
    return __builtin_amdgcn_mfma_f32_16x16x32_bf16(a, b, c, 0, 0, 0);
}

// ======================= point binning: Morton 16x16x16 =======================
__device__ __forceinline__ int spread3(int v) {
    return (v & 1) | ((v & 2) << 2) | ((v & 4) << 4) | ((v & 8) << 6);
}

__global__ __launch_bounds__(256) void bin_count(
    const float* __restrict__ x, int* __restrict__ hist, int* __restrict__ binOf)
{
    int p = blockIdx.x * 256 + threadIdx.x;
    float X = x[3*p+0], Y = x[3*p+1], Z = x[3*p+2];
    int bx = min(max((int)((X + 1.0f) * 8.0f), 0), 15);
    int by = min(max((int)((Y + 1.0f) * 8.0f), 0), 15);
    int bz = min(max((int)((Z + 1.0f) * 8.0f), 0), 15);
    int bin = spread3(bx) | (spread3(by) << 1) | (spread3(bz) << 2);
    binOf[p] = bin;
    atomicAdd(&hist[bin], 1);
}

__global__ __launch_bounds__(1024) void scan_bins(
    const int* __restrict__ hist, int* __restrict__ cursor)
{
    __shared__ int a[1024];
    int t = threadIdx.x;
    int h0 = hist[4*t+0], h1 = hist[4*t+1], h2 = hist[4*t+2], h3 = hist[4*t+3];
    int s = h0 + h1 + h2 + h3;
    a[t] = s;
    __syncthreads();
    #pragma unroll
    for (int off = 1; off < 1024; off <<= 1) {
        int v = a[t];
        if (t >= off) v += a[t - off];
        __syncthreads();
        a[t] = v;
        __syncthreads();
    }
    int base = a[t] - s;
    cursor[4*t+0] = base;
    cursor[4*t+1] = base + h0;
    cursor[4*t+2] = base + h0 + h1;
    cursor[4*t+3] = base + h0 + h1 + h2;
}

__global__ __launch_bounds__(256) void scatter_pts(
    const int* __restrict__ binOf, int* __restrict__ cursor, int* __restrict__ perm)
{
    int p = blockIdx.x * 256 + threadIdx.x;
    int pos = atomicAdd(&cursor[binOf[p]], 1);
    perm[pos] = p;
}

// ---------------- planes (C,H,W) fp32 -> (H,W,C) bf16 ----------------
__global__ __launch_bounds__(256) void transpose_bf16(Planes9 pls, short* __restrict__ dst)
{
    __shared__ float tile[64 * 65];
    int b = blockIdx.x;
    int g = b / 1344, rem = b % 1344;
    int r, t2;
    if (rem < 64)       { r = 0; t2 = rem; }
    else if (rem < 320) { r = 1; t2 = rem - 64; }
    else                { r = 2; t2 = rem - 320; }
    int L = 64 << r;
    int wt = L >> 6;
    int y = t2 / wt, xt = t2 % wt;
    const float* sp = pls.p[g * 3 + r];
    short* dp = dst + (size_t)g * 5505024 + (r == 0 ? 0 : (r == 1 ? 262144 : 1310720));
    int t = threadIdx.x;
    int rowbase = y * L + xt * 64;
    {
        int xi = t & 63, cq = t >> 6;
        #pragma unroll
        for (int cc = 0; cc < 16; ++cc) {
            int c = cq * 16 + cc;
            tile[c * 65 + xi] = sp[(size_t)c * L * L + rowbase + xi];
        }
    }
    __syncthreads();
    {
        int ci = t & 63, xq = t >> 6;
        #pragma unroll
        for (int xx = 0; xx < 16; ++xx) {
            int xcol = xq * 16 + xx;
            dp[(size_t)(rowbase + xcol) * 64 + ci] = f2bf(tile[ci * 65 + xcol]);
        }
    }
}

// per-plane bilerp geometry (bf16 transposed planes); kh in 0..7 -> 8-ch slice
__device__ __forceinline__ void plane_geom(
    int pl, float xc0, float xc1, float xc2, const short* __restrict__ tpl, int kh,
    float& wnw, float& wne, float& wsw, float& wse,
    const short*& pNW, const short*& pNE, const short*& pSW, const short*& pSE)
{
    const int grp = (pl >= 6) ? 2 : (pl >= 3 ? 1 : 0);
    const int r = pl - grp * 3;
    const int L = 64 << r;
    const float u = (grp == 2) ? xc1 : xc0;
    const float v = (grp == 0) ? xc1 : xc2;
    float ix = (u + 1.0f) * 0.5f * (float)(L - 1);
    float iy = (v + 1.0f) * 0.5f * (float)(L - 1);
    float ix0 = floorf(ix), iy0 = floorf(iy);
    float wx = ix - ix0, wy = iy - iy0;
    int x0 = (int)fminf(fmaxf(ix0, 0.f), (float)(L-1));
    int x1 = (int)fminf(fmaxf(ix0+1.f, 0.f), (float)(L-1));
    int y0 = (int)fminf(fmaxf(iy0, 0.f), (float)(L-1));
    int y1 = (int)fminf(fmaxf(iy0+1.f, 0.f), (float)(L-1));
    wnw = (1.f-wx)*(1.f-wy); wne = wx*(1.f-wy); wsw = (1.f-wx)*wy; wse = wx*wy;
    const short* TP = tpl + (size_t)grp * 5505024
                    + (r == 0 ? 0u : (r == 1 ? 262144u : 1310720u));
    pNW = TP + ((size_t)(y0*L + x0) * 64 + kh*8);
    pNE = TP + ((size_t)(y0*L + x1) * 64 + kh*8);
    pSW = TP + ((size_t)(y1*L + x0) * 64 + kh*8);
    pSE = TP + ((size_t)(y1*L + x1) * 64 + kh*8);
}

// ===== fused kernel v12: fused11 + LDS geom table (R11-validated numerics), =====
// ===== isolated on the validated single-plane-loop structure.                 =====
// LDS: [0,32768) hB/feat-dbuf; [32768,41984) geomW f32x4[576]; [41984,46592) geomM uint2[576]
__global__ __launch_bounds__(512, 4) void fused12(
    const float* __restrict__ x, const short* __restrict__ tpl,
    const int* __restrict__ perm,
    const short* __restrict__ W1h,
    const short* __restrict__ W2h,
    const short* __restrict__ Wlh,
    const float* __restrict__ b1, const float* __restrict__ b2, const float* __restrict__ bl,
    float* __restrict__ out)
{
    __shared__ __align__(16) char smem[46592];
    __shared__ float xs[192];
    const int t = threadIdx.x;
    // XCD swizzle: hw blockIdx b -> data block (b%8)*256 + b/8  (2048 = 8 * 256, bijective)
    const int blk = ((blockIdx.x & 7) << 8) | (blockIdx.x >> 3);
    if (t < 64) {
        int pi = perm[blk * 64 + t];
        xs[3*t+0] = x[3*pi+0];
        xs[3*t+1] = x[3*pi+1];
        xs[3*t+2] = x[3*pi+2];
    }
    const int w = t >> 6, ln = t & 63, s = ln & 15, g = ln >> 4;
    const int swz = (s & 7) << 4;
    const int pt = t >> 3, kh = t & 7;        // 8 consecutive lanes per point
    const int ptswz = (pt & 7) << 4;
    __syncthreads();   // xs visible

    // ---- geom table: one entry per (plane, point), computed ONCE (R11 numerics) ----
    #pragma unroll 1
    for (int e = t; e < 576; e += 512) {
        int pl = e >> 6, pp = e & 63;
        float xc0 = xs[pp*3+0], xc1 = xs[pp*3+1], xc2 = xs[pp*3+2];
        int grp = (pl >= 6) ? 2 : (pl >= 3 ? 1 : 0);
        int r = pl - grp * 3;
        int L = 64 << r;
        float u = (grp == 2) ? xc1 : xc0;
        float v = (grp == 0) ? xc1 : xc2;
        float ix = (u + 1.0f) * 0.5f * (float)(L - 1);
        float iy = (v + 1.0f) * 0.5f * (float)(L - 1);
        float ix0 = floorf(ix), iy0 = floorf(iy);
        float wx = ix - ix0, wy = iy - iy0;
        int x0 = (int)fminf(fmaxf(ix0, 0.f), (float)(L-1));
        int x1 = (int)fminf(fmaxf(ix0+1.f, 0.f), (float)(L-1));
        int y0 = (int)fminf(fmaxf(iy0, 0.f), (float)(L-1));
        int y1 = (int)fminf(fmaxf(iy0+1.f, 0.f), (float)(L-1));
        f32x4 wv;
        wv[0] = (1.f-wx)*(1.f-wy); wv[1] = wx*(1.f-wy);
        wv[2] = (1.f-wx)*wy;       wv[3] = wx*wy;
        unsigned grpoff = (unsigned)grp * 5505024u + (r == 0 ? 0u : (r == 1 ? 262144u : 1310720u));
        unsigned base = (grpoff + (unsigned)(y0*L + x0) * 64u) * 2u;
        unsigned dx = (unsigned)(x1 - x0) * 128u;
        unsigned dy = (unsigned)((y1 - y0) * L) * 128u;
        *(f32x4*)(smem + 32768 + e*16) = wv;
        uint2 mm2; mm2.x = base; mm2.y = dx | (dy << 16);
        *(uint2*)(smem + 41984 + e*8) = mm2;
    }

    f32x4 acc[4][2];
    const f32x4 fz = {0.f, 0.f, 0.f, 0.f};
    #pragma unroll
    for (int mt = 0; mt < 4; ++mt)
        #pragma unroll
        for (int j = 0; j < 2; ++j) acc[mt][j] = fz;
    __syncthreads();   // geom table ready

    // two named prefetch slots (depth-2 pipeline), static indexing only
    f32x4 wA, wB;
    i32x4 preA[4], preB[4];

#define ISSUE(SL, PL) do { \
        int e_ = (PL)*64 + pt; \
        w##SL = *(const f32x4*)(smem + 32768 + e_*16); \
        uint2 m_ = *(const uint2*)(smem + 41984 + e_*8); \
        const char* pb_ = (const char*)tpl + m_.x + kh*16; \
        unsigned dx_ = m_.y & 0xffffu, dy_ = m_.y >> 16; \
        pre##SL[0] = *(const i32x4*)pb_; \
        pre##SL[1] = *(const i32x4*)(pb_ + dx_); \
        pre##SL[2] = *(const i32x4*)(pb_ + dy_); \
        pre##SL[3] = *(const i32x4*)(pb_ + dx_ + dy_); \
    } while (0)
#define INTERP(SL, FB) do { \
        s16x8 hi8; \
        _Pragma("unroll") \
        for (int q = 0; q < 4; ++q) { \
            f32x2 v = upk2((unsigned)pre##SL[0][q]) * w##SL[0] \
                    + upk2((unsigned)pre##SL[1][q]) * w##SL[1] \
                    + upk2((unsigned)pre##SL[2][q]) * w##SL[2] \
                    + upk2((unsigned)pre##SL[3][q]) * w##SL[3]; \
            hi8[q*2]   = f2bf_fast(v[0]); \
            hi8[q*2+1] = f2bf_fast(v[1]); \
        } \
        *(s16x8*)((FB) + pt*128 + ((kh*16) ^ ptswz)) = hi8; \
    } while (0)

    ISSUE(A, 0);
    ISSUE(B, 1);

    // ===== Layer 1: 9 planes, dbuf feat tile, depth-2 prefetch, 1 barrier/plane =====
    #pragma unroll 1
    for (int pl = 0; pl < 9; ++pl) {
        char* fb = smem + ((pl & 1) << 13);
        if (pl & 1) {
            INTERP(B, fb);
            if (pl < 7) ISSUE(B, pl + 2);   // 2 MFMA phases + interp to land
        } else {
            INTERP(A, fb);
            if (pl < 7) ISSUE(A, pl + 2);
        }
        __syncthreads();

        #pragma unroll
        for (int ks = 0; ks < 2; ++ks) {
            s16x8 B[4];
            #pragma unroll
            for (int mt = 0; mt < 4; ++mt)
                B[mt] = *(s16x8*)(fb + (mt*16 + s)*128 + ((ks*64 + g*16) ^ swz));
            #pragma unroll
            for (int j = 0; j < 2; ++j) {
                size_t ro = (size_t)((8*j + w)*16 + s) * 576 + (size_t)(pl*64 + ks*32 + g*8);
                s16x8 Ah = *(const s16x8*)(W1h + ro);
                #pragma unroll
                for (int mt = 0; mt < 4; ++mt)
                    acc[mt][j] = mm(Ah, B[mt], acc[mt][j]);
            }
        }
    }
#undef ISSUE
#undef INTERP
    __syncthreads();   // all MFMA reads of feat bufs done before hB overwrite

    // ======== bias + softplus, stage h1 (bf16) to hB [64 pt][256 k] ========
    #pragma unroll
    for (int j = 0; j < 2; ++j) {
        f32x4 bv = *(const f32x4*)(b1 + (8*j + w)*16 + g*4);
        #pragma unroll
        for (int mt = 0; mt < 4; ++mt) {
            f32x4 a = acc[mt][j];
            s16x4 hq;
            hq[0] = f2bf_fast(sp100f((a[0] + bv[0]) * 100.0f));
            hq[1] = f2bf_fast(sp100f((a[1] + bv[1]) * 100.0f));
            hq[2] = f2bf_fast(sp100f((a[2] + bv[2]) * 100.0f));
            hq[3] = f2bf_fast(sp100f((a[3] + bv[3]) * 100.0f));
            int off = (mt*16 + s)*512 + ((((8*j + w)*32) + g*8) ^ swz);
            *(s16x4*)(smem + off) = hq;
        }
    }
    #pragma unroll
    for (int mt = 0; mt < 4; ++mt)
        #pragma unroll
        for (int j = 0; j < 2; ++j) acc[mt][j] = fz;
    __syncthreads();

    // ---------------- Layer 2: K = 256, W-hi only ----------------
    #pragma unroll 1
    for (int ks = 0; ks < 8; ++ks) {
        s16x8 B[4];
        #pragma unroll
        for (int mt = 0; mt < 4; ++mt) {
            int off = (mt*16 + s)*512 + ((ks*64 + g*16) ^ swz);
            B[mt] = *(s16x8*)(smem + off);
        }
        #pragma unroll
        for (int j = 0; j < 2; ++j) {
            size_t ro = (size_t)((8*j + w)*16 + s) * 256 + (size_t)(ks*32 + g*8);
            s16x8 Ah = *(const s16x8*)(W2h + ro);
            #pragma unroll
            for (int mt = 0; mt < 4; ++mt)
                acc[mt][j] = mm(Ah, B[mt], acc[mt][j]);
        }
    }
    __syncthreads();   // all hB reads done before overwrite with h2

    // ======== bias + softplus, stage h2 ========
    #pragma unroll
    for (int j = 0; j < 2; ++j) {
        f32x4 bv = *(const f32x4*)(b2 + (8*j + w)*16 + g*4);
        #pragma unroll
        for (int mt = 0; mt < 4; ++mt) {
            f32x4 a = acc[mt][j];
            s16x4 hq;
            hq[0] = f2bf_fast(sp100f((a[0] + bv[0]) * 100.0f));
            hq[1] = f2bf_fast(sp100f((a[1] + bv[1]) * 100.0f));
            hq[2] = f2bf_fast(sp100f((a[2] + bv[2]) * 100.0f));
            hq[3] = f2bf_fast(sp100f((a[3] + bv[3]) * 100.0f));
            int off = (mt*16 + s)*512 + ((((8*j + w)*32) + g*8) ^ swz);
            *(s16x4*)(smem + off) = hq;
        }
    }
    __syncthreads();

    // ------- Layer 3: Wl padded to 128 rows (8 tiles); wave w owns tile w -------
    f32x4 acc3[4];
    #pragma unroll
    for (int mt = 0; mt < 4; ++mt) acc3[mt] = fz;
    #pragma unroll 1
    for (int ks = 0; ks < 8; ++ks) {
        s16x8 B[4];
        #pragma unroll
        for (int mt = 0; mt < 4; ++mt) {
            int off = (mt*16 + s)*512 + ((ks*64 + g*16) ^ swz);
            B[mt] = *(s16x8*)(smem + off);
        }
        size_t ro = (size_t)(w*16 + s) * 256 + (size_t)(ks*32 + g*8);
        s16x8 Ah = *(const s16x8*)(Wlh + ro);
        #pragma unroll
        for (int mt = 0; mt < 4; ++mt)
            acc3[mt] = mm(Ah, B[mt], acc3[mt]);
    }

    // ---------------- output: feat (P,64) + dsdf (P,1), perm-scattered ----------------
    if (w < 4) {
        f32x4 bv = *(const f32x4*)(bl + w*16 + g*4);
        #pragma unroll
        for (int mt = 0; mt < 4; ++mt) {
            int pl_ = blk*64 + mt*16 + s;
            size_t p = (size_t)perm[pl_];
            f32x4 o = acc3[mt];
            o[0] += bv[0]; o[1] += bv[1]; o[2] += bv[2]; o[3] += bv[3];
            *(f32x4*)(out + p*64 + (size_t)(w*16 + g*4)) = o;
        }
    } else if (w == 4 && g == 0) {
        float bld = bl[64];
        #pragma unroll
        for (int mt = 0; mt < 4; ++mt) {
            int pl_ = blk*64 + mt*16 + s;
            size_t p = (size_t)perm[pl_];
            out[(size_t)NPTS*64 + p] = acc3[mt][0] + bld;
        }
    }
}

// ================= fallback (R6-validated, fp32 planes, identity order, split W) =====
__global__ __launch_bounds__(256, 4) void fused3f(
    const float* __restrict__ x, Planes9 pls,
    const short* __restrict__ W1h, const short* __restrict__ W1l,
    const short* __restrict__ W2h, const short* __restrict__ W2l,
    const short* __restrict__ Wlh, const short* __restrict__ Wll,
    const float* __restrict__ b1, const float* __restrict__ b2, const float* __restrict__ bl,
    float* __restrict__ out)
{
    __shared__ __align__(16) char smem[32768];
    __shared__ float xs[192];
    const int t = threadIdx.x, blk = blockIdx.x;
    if (t < 64) {
        int pi = blk * 64 + t;
        xs[3*t+0] = x[3*pi+0];
        xs[3*t+1] = x[3*pi+1];
        xs[3*t+2] = x[3*pi+2];
    }
    const int w = t >> 6, ln = t & 63, s = ln & 15, g = ln >> 4;
    const int swz = (s & 7) << 4;
    const int pt = t & 63, kh = t >> 6;
    const int ptswz = (pt & 7) << 4;

    f32x4 acc[4][4];
    const f32x4 fz = {0.f, 0.f, 0.f, 0.f};
    #pragma unroll
    for (int mt = 0; mt < 4; ++mt)
        #pragma unroll
        for (int j = 0; j < 4; ++j) acc[mt][j] = fz;
    __syncthreads();

    #pragma unroll 1
    for (int pl = 0; pl < 9; ++pl) {
        const int grp = (pl >= 6) ? 2 : (pl >= 3 ? 1 : 0);
        const int r = pl - grp * 3;
        const int L = 64 << r;
        float u, v;
        { float a0 = xs[pt*3+0], a1 = xs[pt*3+1], a2 = xs[pt*3+2];
          u = (grp == 2) ? a1 : a0;
          v = (grp == 0) ? a1 : a2; }
        float ix = (u + 1.0f) * 0.5f * (float)(L - 1);
        float iy = (v + 1.0f) * 0.5f * (float)(L - 1);
        float ix0 = floorf(ix), iy0 = floorf(iy);
        float wx = ix - ix0, wy = iy - iy0;
        int x0 = (int)fminf(fmaxf(ix0, 0.f), (float)(L-1));
        int x1 = (int)fminf(fmaxf(ix0+1.f, 0.f), (float)(L-1));
        int y0 = (int)fminf(fmaxf(iy0, 0.f), (float)(L-1));
        int y1 = (int)fminf(fmaxf(iy0+1.f, 0.f), (float)(L-1));
        float wnw = (1.f-wx)*(1.f-wy), wne = wx*(1.f-wy), wsw = (1.f-wx)*wy, wse = wx*wy;

        const float* P = pls.p[pl];
        const int i00 = y0*L+x0, i01 = y0*L+x1, i10 = y1*L+x0, i11 = y1*L+x1;
        float f[16];
        #pragma unroll 8
        for (int c = 0; c < 16; ++c) {
            const float* pc = P + (size_t)(kh*16 + c) * L * L;
            f[c] = wnw*pc[i00] + wne*pc[i01] + wsw*pc[i10] + wse*pc[i11];
        }
        #pragma unroll
        for (int q = 0; q < 2; ++q) {
            s16x8 hi8;
            #pragma unroll
            for (int e = 0; e < 8; ++e) hi8[e] = f2bf_fast(f[q*8+e]);
            int off = pt*128 + ((kh*32 + q*16) ^ ptswz);
            *(s16x8*)(smem + off) = hi8;
        }
        __syncthreads();

        #pragma unroll
        for (int ks = 0; ks < 2; ++ks) {
            s16x8 B[4];
            #pragma unroll
            for (int mt = 0; mt < 4; ++mt)
                B[mt] = *(s16x8*)(smem + (mt*16 + s)*128 + ((ks*64 + g*16) ^ swz));
            #pragma unroll
            for (int j = 0; j < 4; ++j) {
                size_t ro = (size_t)((4*j + w)*16 + s) * 576 + (size_t)(pl*64 + ks*32 + g*8);
                s16x8 Ah = *(const s16x8*)(W1h + ro);
                s16x8 Al = *(const s16x8*)(W1l + ro);
                #pragma unroll
                for (int mt = 0; mt < 4; ++mt) {
                    acc[mt][j] = mm(Ah, B[mt], acc[mt][j]);
                    acc[mt][j] = mm(Al, B[mt], acc[mt][j]);
                }
            }
        }
        __syncthreads();
    }

    #pragma unroll
    for (int j = 0; j < 4; ++j) {
        f32x4 bv = *(const f32x4*)(b1 + (4*j + w)*16 + g*4);
        #pragma unroll
        for (int mt = 0; mt < 4; ++mt) {
            f32x4 a = acc[mt][j];
            s16x4 hq;
            hq[0] = f2bf_fast(sp100(a[0] + bv[0]));
            hq[1] = f2bf_fast(sp100(a[1] + bv[1]));
            hq[2] = f2bf_fast(sp100(a[2] + bv[2]));
            hq[3] = f2bf_fast(sp100(a[3] + bv[3]));
            int off = (mt*16 + s)*512 + ((((4*j + w)*32) + g*8) ^ swz);
            *(s16x4*)(smem + off) = hq;
        }
    }
    #pragma unroll
    for (int mt = 0; mt < 4; ++mt)
        #pragma unroll
        for (int j = 0; j < 4; ++j) acc[mt][j] = fz;
    __syncthreads();

    #pragma unroll 1
    for (int ks = 0; ks < 8; ++ks) {
        s16x8 B[4];
        #pragma unroll
        for (int mt = 0; mt < 4; ++mt)
            B[mt] = *(s16x8*)(smem + (mt*16 + s)*512 + ((ks*64 + g*16) ^ swz));
        #pragma unroll
        for (int j = 0; j < 4; ++j) {
            size_t ro = (size_t)((4*j + w)*16 + s) * 256 + (size_t)(ks*32 + g*8);
            s16x8 Ah = *(const s16x8*)(W2h + ro);
            s16x8 Al = *(const s16x8*)(W2l + ro);
            #pragma unroll
            for (int mt = 0; mt < 4; ++mt) {
                acc[mt][j] = mm(Ah, B[mt], acc[mt][j]);
                acc[mt][j] = mm(Al, B[mt], acc[mt][j]);
            }
        }
    }
    __syncthreads();

    #pragma unroll
    for (int j = 0; j < 4; ++j) {
        f32x4 bv = *(const f32x4*)(b2 + (4*j + w)*16 + g*4);
        #pragma unroll
        for (int mt = 0; mt < 4; ++mt) {
            f32x4 a = acc[mt][j];
            s16x4 hq;
            hq[0] = f2bf_fast(sp100(a[0] + bv[0]));
            hq[1] = f2bf_fast(sp100(a[1] + bv[1]));
            hq[2] = f2bf_fast(sp100(a[2] + bv[2]));
            hq[3] = f2bf_fast(sp100(a[3] + bv[3]));
            int off = (mt*16 + s)*512 + ((((4*j + w)*32) + g*8) ^ swz);
            *(s16x4*)(smem + off) = hq;
        }
    }
    __syncthreads();

    f32x4 acc3[4][2];
    #pragma unroll
    for (int mt = 0; mt < 4; ++mt) { acc3[mt][0] = fz; acc3[mt][1] = fz; }
    #pragma unroll 1
    for (int ks = 0; ks < 8; ++ks) {
        s16x8 B[4];
        #pragma unroll
        for (int mt = 0; mt < 4; ++mt)
            B[mt] = *(s16x8*)(smem + (mt*16 + s)*512 + ((ks*64 + g*16) ^ swz));
        #pragma unroll
        for (int j = 0; j < 2; ++j) {
            size_t ro = (size_t)((4*j + w)*16 + s) * 256 + (size_t)(ks*32 + g*8);
            s16x8 Ah = *(const s16x8*)(Wlh + ro);
            s16x8 Al = *(const s16x8*)(Wll + ro);
            #pragma unroll
            for (int mt = 0; mt < 4; ++mt) {
                acc3[mt][j] = mm(Ah, B[mt], acc3[mt][j]);
                acc3[mt][j] = mm(Al, B[mt], acc3[mt][j]);
            }
        }
    }

    {
        f32x4 bv = *(const f32x4*)(bl + w*16 + g*4);
        #pragma unroll
        for (int mt = 0; mt < 4; ++mt) {
            size_t p = (size_t)(blk*64 + mt*16 + s);
            f32x4 o = acc3[mt][0];
            o[0] += bv[0]; o[1] += bv[1]; o[2] += bv[2]; o[3] += bv[3];
            *(f32x4*)(out + p*64 + (size_t)(w*16 + g*4)) = o;
            if (w == 0 && g == 0)
                out[(size_t)NPTS*64 + p] = acc3[mt][1][0] + bl[64];
        }
    }
}

// ---------------- weight-norm + bf16 hi/lo split (row-major n x k) -------
__global__ __launch_bounds__(64) void prep_weights(
    const float* __restrict__ v1, const float* __restrict__ g1,
    const float* __restrict__ v2, const float* __restrict__ g2,
    const float* __restrict__ vl, const float* __restrict__ gl,
    short* __restrict__ W1h, short* __restrict__ W1l,
    short* __restrict__ W2h, short* __restrict__ W2l,
    short* __restrict__ Wlh, short* __restrict__ Wll)
{
    int i = blockIdx.x, t = threadIdx.x;
    const float* src; float gv; int K; short *dh, *dl; size_t ro;
    if (i < 256)      { src = v1 + (size_t)i*576; gv = g1[i]; K = 576; dh = W1h; dl = W1l; ro = (size_t)i*576; }
    else if (i < 512) { int rr = i-256; src = v2 + (size_t)rr*256; gv = g2[rr]; K = 256; dh = W2h; dl = W2l; ro = (size_t)rr*256; }
    else {
        int rr = i-512;
        K = 256; dh = Wlh; dl = Wll; ro = (size_t)rr*256;
        if (rr >= 65) {
            for (int k = t; k < 256; k += 64) { dh[ro+k] = 0; dl[ro+k] = 0; }
            return;
        }
        src = vl + (size_t)rr*256; gv = gl[rr];
    }
    float ssum = 0.f;
    for (int k = t; k < K; k += 64) { float wv = src[k]; ssum += wv*wv; }
    #pragma unroll
    for (int off = 32; off > 0; off >>= 1) ssum += __shfl_xor(ssum, off, 64);
    float sc = gv / sqrtf(ssum);
    for (int k = t; k < K; k += 64) {
        float wv = src[k] * sc;
        short hb = f2bf(wv);
        dh[ro + k] = hb;
        dl[ro + k] = f2bf(wv - bf2f(hb));
    }
}

extern "C" void kernel_launch(void* const* d_in, const int* in_sizes, int n_in,
                              void* d_out, int out_size, void* d_ws, size_t ws_size,
                              hipStream_t stream)
{
    const float* x = (const float*)d_in[0];
    Planes9 pls;
    for (int i = 0; i < 9; ++i) pls.p[i] = (const float*)d_in[1 + i];
    const float* v1 = (const float*)d_in[10];
    const float* g1 = (const float*)d_in[11];
    const float* b1 = (const float*)d_in[12];
    const float* v2 = (const float*)d_in[13];
    const float* g2 = (const float*)d_in[14];
    const float* b2 = (const float*)d_in[15];
    const float* vl = (const float*)d_in[16];
    const float* gl = (const float*)d_in[17];
    const float* bl = (const float*)d_in[18];

    short* ws16 = (short*)d_ws;
    short* W1h = ws16;                    // 256*576
    short* W1l = ws16 + 147456;
    short* W2h = ws16 + 294912;           // 256*256
    short* W2l = ws16 + 360448;
    short* Wlh = ws16 + 425984;           // 128*256 (padded)
    short* Wll = ws16 + 458752;
    short* tpl = ws16 + 491520;           // bf16 transposed planes: 16515072 shorts
    const size_t w_bytes   = (size_t)491520 * 2;
    const size_t tpl_bytes = (size_t)16515072 * 2;
    int* hist   = (int*)((char*)d_ws + w_bytes + tpl_bytes);
    int* cursor = hist + 4096;
    int* binOf  = cursor + 4096;
    int* perm   = binOf + 131072;
    const size_t need = w_bytes + tpl_bytes + (4096*2 + 131072*2) * sizeof(int);

    prep_weights<<<640, 64, 0, stream>>>(v1, g1, v2, g2, vl, gl,
                                         W1h, W1l, W2h, W2l, Wlh, Wll);

    if (ws_size >= need) {
        transpose_bf16<<<4032, 256, 0, stream>>>(pls, tpl);
        hipError_t e = hipMemsetAsync(hist, 0, 4096 * sizeof(int), stream); (void)e;
        bin_count<<<NPTS / 256, 256, 0, stream>>>(x, hist, binOf);
        scan_bins<<<1, 1024, 0, stream>>>(hist, cursor);
        scatter_pts<<<NPTS / 256, 256, 0, stream>>>(binOf, cursor, perm);
        fused12<<<NPTS / 64, 512, 0, stream>>>(x, tpl, perm,
                                               W1h, W2h, Wlh,
                                               b1, b2, bl, (float*)d_out);
    } else {
        fused3f<<<NPTS / 64, 256, 0, stream>>>(x, pls,
                                               W1h, W1l, W2h, W2l, Wlh, Wll,
                                               b1, b2, bl, (float*)d_out);
    }
}